// Round 35
// baseline (214.890 us; speedup 1.0000x reference)
//
#include <hip/hip_runtime.h>
#include <cstddef>
#include <cmath>

#define BATCH 2
#define LSEQ 2048
#define DM 1024
#define DSTATE 16
#define DI 2048
#define DTR 64
#define XDR 96   // DTR + 2*DSTATE
#define NC 64    // scan chunks
#define TC 32    // timesteps per chunk (NC*TC == LSEQ)
#define PN (4096 * 96)  // per-z x_dbl partial size

using f32x4 = __attribute__((ext_vector_type(4))) float;
using bf16x8 = __attribute__((ext_vector_type(8))) short;

__device__ __forceinline__ unsigned short f2bf(float f) {
  union { float f; unsigned int u; } c; c.f = f;
  unsigned int u = c.u;
  return (unsigned short)((u + 0x7FFFu + ((u >> 16) & 1u)) >> 16);  // RNE
}
__device__ __forceinline__ float bf2f(unsigned short h) {
  union { unsigned int u; float f; } c; c.u = ((unsigned int)h) << 16;
  return c.f;
}
__device__ __forceinline__ unsigned int pack2(float a, float b) {
  return (unsigned int)f2bf(a) | ((unsigned int)f2bf(b) << 16);
}

__device__ __forceinline__ void gl_lds16(const void* g, void* l) {
  __builtin_amdgcn_global_load_lds(
      (const __attribute__((address_space(1))) void*)g,
      (__attribute__((address_space(3))) void*)l, 16, 0, 0);
}

__device__ __forceinline__ float softplus_fast(float x) {
  float ex = __expf(x);
  return (x > 20.f) ? x : __logf(1.f + ex);
}

// dA[n] = q^(n+1), binary-power tree (depth ~4 instead of 15-serial).
__device__ __forceinline__ void pow_tree(float q1, float* dA) {
  float q2 = q1 * q1;
  float q3 = q2 * q1;
  float q4 = q2 * q2;
  float q8 = q4 * q4;
  float q5 = q4 * q1, q6 = q4 * q2, q7 = q4 * q3;
  dA[0] = q1;  dA[1] = q2;  dA[2] = q3;  dA[3] = q4;
  dA[4] = q5;  dA[5] = q6;  dA[6] = q7;  dA[7] = q8;
  dA[8] = q8 * q1;  dA[9] = q8 * q2;  dA[10] = q8 * q3;  dA[11] = q8 * q4;
  dA[12] = q8 * q5; dA[13] = q8 * q6; dA[14] = q8 * q7;  dA[15] = q8 * q8;
}

// ---------------------------------------------------------------------------
// Single-launch f32->bf16 conversion of ALL seven GEMM operands.
// ---------------------------------------------------------------------------
#define G_HS   524288            // BLM/8
#define G_IN2  (G_HS + 524288)
#define G_W1   (G_IN2 + 262144)  // WN/8
#define G_W2   (G_W1 + 262144)
#define G_XPW  (G_W2 + 24576)    // XDR*DI/8
#define G_DTW  (G_XPW + 16384)   // DI*DTR/8
#define G_OW   (G_DTW + 262144)  // total 1,875,968 -> 7328 blocks exactly

__global__ __launch_bounds__(256) void cvt_all_kernel(
    const float* __restrict__ hs, const float* __restrict__ in2,
    const float* __restrict__ w1, const float* __restrict__ w2,
    const float* __restrict__ xpw, const float* __restrict__ dtw,
    const float* __restrict__ ow, unsigned short* __restrict__ hsb,
    unsigned short* __restrict__ in2b, unsigned short* __restrict__ wb1,
    unsigned short* __restrict__ wb2, unsigned short* __restrict__ xpwB,
    unsigned short* __restrict__ dtwB, unsigned short* __restrict__ owb) {
  int i = blockIdx.x * 256 + threadIdx.x;
  const float* s;
  unsigned short* d;
  int k;
  if (i < G_HS)       { s = hs;  d = hsb;  k = i; }
  else if (i < G_IN2) { s = in2; d = in2b; k = i - G_HS; }
  else if (i < G_W1)  { s = w1;  d = wb1;  k = i - G_IN2; }
  else if (i < G_W2)  { s = w2;  d = wb2;  k = i - G_W1; }
  else if (i < G_XPW) { s = xpw; d = xpwB; k = i - G_W2; }
  else if (i < G_DTW) { s = dtw; d = dtwB; k = i - G_XPW; }
  else                { s = ow;  d = owb;  k = i - G_DTW; }
  const float4* sp = reinterpret_cast<const float4*>(s) + (size_t)k * 2;
  float4 a = sp[0], b = sp[1];
  uint4 v = make_uint4(pack2(a.x, a.y), pack2(a.z, a.w), pack2(b.x, b.y),
                       pack2(b.z, b.w));
  *(reinterpret_cast<uint4*>(d) + k) = v;
}

// ---------------------------------------------------------------------------
// Dual in-proj GEMM, 4-phase 256^2 counted-vmcnt schedule.
// BM=BN=256, BK=64, 8 waves (2M x 4N), 512 threads, 128 KiB LDS (2 K-tile
// double buffer).  Per phase: one A-half (4 m-frags) x K=64 = 32 MFMA.
// Stage schedule (target freed by an earlier phase-end barrier):
//   phA: T+1.A -> buf1.A (freed prev phD)   phB: T+2.B -> buf0.B (phA)
//   phC: T+2.A -> buf0.A (phB)              phD: T+3.B -> buf1.B (phC)
// vmcnt(4) at phB/phD (4 loads = 1 tile stay in flight, never 0 in loop).
// ---------------------------------------------------------------------------
__global__ __launch_bounds__(512) void gemm_in12(
    const unsigned short* __restrict__ A0, const unsigned short* __restrict__ B0,
    unsigned short* __restrict__ C0, const unsigned short* __restrict__ A1,
    const unsigned short* __restrict__ B1, unsigned short* __restrict__ C1) {
  __shared__ __align__(16) unsigned short Asm[2][256][64];  // 64 KiB
  __shared__ __align__(16) unsigned short Bsm[2][256][64];  // 64 KiB

  const unsigned short* A = blockIdx.z ? A1 : A0;
  const unsigned short* B = blockIdx.z ? B1 : B0;
  unsigned short* C = blockIdx.z ? C1 : C0;
  const int lda = DM, ldc = DI;  // K = DM = 1024 -> 16 K-tiles of 64

  const int tid = threadIdx.x;
  const int lane = tid & 63;
  const int w = tid >> 6;   // 0..7
  const int wr = w >> 2;    // 0..1  (M half)
  const int wn = w & 3;     // 0..3  (N quarter)

  const int gx = gridDim.x;            // 8
  const int nwg = gx * gridDim.y;      // 128 (per z)
  const int id = blockIdx.y * gx + blockIdx.x;
  const int cpx = nwg >> 3;
  const int lt = (id & 7) * cpx + (id >> 3);
  const size_t m0 = (size_t)(lt / gx) * 256;
  const size_t n0 = (size_t)(lt % gx) * 256;

  const int rsub = lane >> 3;
  const int sslot = (lane & 7) ^ rsub;
  const unsigned short* Ab = A + (m0 + (size_t)rsub) * lda + sslot * 8;
  const unsigned short* Bb = B + (n0 + (size_t)rsub) * lda + sslot * 8;

  const int fr = lane & 15;
  const int q = lane >> 4;
  const int f7 = fr & 7;

  f32x4 acc[8][4] = {};
  bf16x8 bfr[4][2];

// stage a full 256x64 tile of K-tile T: each wave fills 32 rows (4 gl_lds)
#define STA(BUF, T)                                                         \
  {                                                                         \
    const int r0_ = w * 32;                                                 \
    const unsigned short* s_ = Ab + (size_t)r0_ * lda + (T) * 64;           \
    gl_lds16(s_, &Asm[BUF][r0_][0]);                                        \
    gl_lds16(s_ + (size_t)8 * lda, &Asm[BUF][r0_ + 8][0]);                  \
    gl_lds16(s_ + (size_t)16 * lda, &Asm[BUF][r0_ + 16][0]);                \
    gl_lds16(s_ + (size_t)24 * lda, &Asm[BUF][r0_ + 24][0]);                \
  }
#define STB(BUF, T)                                                         \
  {                                                                         \
    const int r0_ = w * 32;                                                 \
    const unsigned short* s_ = Bb + (size_t)r0_ * lda + (T) * 64;           \
    gl_lds16(s_, &Bsm[BUF][r0_][0]);                                        \
    gl_lds16(s_ + (size_t)8 * lda, &Bsm[BUF][r0_ + 8][0]);                  \
    gl_lds16(s_ + (size_t)16 * lda, &Bsm[BUF][r0_ + 16][0]);                \
    gl_lds16(s_ + (size_t)24 * lda, &Bsm[BUF][r0_ + 24][0]);                \
  }

// one phase: ds-load half subtile | stage | [vmcnt] | barrier | lgkm0 | MFMA
#define PH4(BUFI, HALF, LOADB, STG, VM)                                     \
  {                                                                         \
    if (LOADB) {                                                            \
      _Pragma("unroll") for (int j = 0; j < 4; ++j)                         \
          _Pragma("unroll") for (int kk = 0; kk < 2; ++kk)                  \
              bfr[j][kk] = *reinterpret_cast<const bf16x8*>(                \
                  &Bsm[BUFI][wn * 64 + j * 16 + fr]                         \
                      [((kk * 4 + q) ^ f7) << 3]);                          \
    }                                                                       \
    bf16x8 af_[4][2];                                                       \
    _Pragma("unroll") for (int mi = 0; mi < 4; ++mi)                        \
        _Pragma("unroll") for (int kk = 0; kk < 2; ++kk)                    \
            af_[mi][kk] = *reinterpret_cast<const bf16x8*>(                 \
                &Asm[BUFI][wr * 128 + ((HALF)*4 + mi) * 16 + fr]            \
                    [((kk * 4 + q) ^ f7) << 3]);                            \
    STG;                                                                    \
    VM;                                                                     \
    __builtin_amdgcn_s_barrier();                                           \
    asm volatile("s_waitcnt lgkmcnt(0)" ::: "memory");                      \
    __builtin_amdgcn_sched_barrier(0);                                      \
    __builtin_amdgcn_s_setprio(1);                                          \
    _Pragma("unroll") for (int kk = 0; kk < 2; ++kk)                        \
        _Pragma("unroll") for (int mi = 0; mi < 4; ++mi)                    \
            _Pragma("unroll") for (int j = 0; j < 4; ++j)                   \
                acc[(HALF)*4 + mi][j] =                                     \
                    __builtin_amdgcn_mfma_f32_16x16x32_bf16(                \
                        af_[mi][kk], bfr[j][kk], acc[(HALF)*4 + mi][j],     \
                        0, 0, 0);                                           \
    __builtin_amdgcn_s_setprio(0);                                          \
    __builtin_amdgcn_s_barrier();                                           \
  }

#define VMC4_ asm volatile("s_waitcnt vmcnt(4)" ::: "memory")
#define VMC0_ asm volatile("s_waitcnt vmcnt(0)" ::: "memory")
#define NOPS_ ((void)0)

  // prologue: T0.B, T0.A, T1.B; drain T0 (T1.B stays in flight)
  STB(0, 0)
  STA(0, 0)
  STB(1, 1)
  VMC4_;
  __builtin_amdgcn_s_barrier();

#pragma unroll 1
  for (int it = 0; it < 7; ++it) {
    const int t0 = 2 * it, t1 = 2 * it + 1;
    PH4(0, 0, true,  STA(1, t1),     NOPS_)   // phA
    PH4(0, 1, false, STB(0, t0 + 2), VMC4_)   // phB: drain T+1.A (+lingering)
    PH4(1, 0, true,  STA(0, t0 + 2), NOPS_)   // phC
    PH4(1, 1, false, STB(1, t1 + 2), VMC4_)   // phD: drain T+2.B + T+2.A
  }
  // final iteration: tiles 14 (buf0), 15 (buf1); no further staging
  PH4(0, 0, true,  STA(1, 15), NOPS_)
  PH4(0, 1, false, NOPS_,      VMC0_)
  PH4(1, 0, true,  NOPS_, NOPS_)
  PH4(1, 1, false, NOPS_, NOPS_)

#undef STA
#undef STB
#undef PH4

  const int crb = q * 4;
#pragma unroll
  for (int mf = 0; mf < 8; ++mf) {
    size_t row = m0 + wr * 128 + mf * 16 + crb;
#pragma unroll
    for (int j = 0; j < 4; ++j) {
      size_t col = n0 + wn * 64 + j * 16 + fr;
#pragma unroll
      for (int r = 0; r < 4; ++r)
        C[(row + r) * ldc + col] = f2bf(acc[mf][j][r]);
    }
  }
}

// ---------------------------------------------------------------------------
// Out-proj GEMM: out[m,n] = sum_k g[m,k]*ow[n,k].  M=4096, N=DM, K=DI.
// BM=128, BN=64 (512 blocks -> 2 blocks/CU), 4 waves, wave tile 64x32.
// f32 out.  Same staging/swizzle idiom.
// ---------------------------------------------------------------------------
__global__ __launch_bounds__(256) void gemm_out(
    const unsigned short* __restrict__ A, const unsigned short* __restrict__ B,
    float* __restrict__ C) {
  __shared__ __align__(16) unsigned short As[128][64];
  __shared__ __align__(16) unsigned short Bs[64][64];

  const int K = DI, lda = DI, ldb = DI, ldc = DM;

  const int tid = threadIdx.x;
  const int lane = tid & 63;
  const int w = tid >> 6;

  const int gx = gridDim.x;  // 16
  const int nwg = gx * gridDim.y;
  const int id = blockIdx.y * gx + blockIdx.x;
  const int cpx = nwg >> 3;
  const int lt = (id & 7) * cpx + (id >> 3);
  const size_t m0 = (size_t)(lt / gx) * 128;
  const size_t n0 = (size_t)(lt % gx) * 64;

  const int rsub = lane >> 3;
  const int sslot = (lane & 7) ^ rsub;
  const unsigned short* Ab = A + m0 * lda + (size_t)rsub * lda + sslot * 8;
  const unsigned short* Bb = B + n0 * ldb + (size_t)rsub * ldb + sslot * 8;

  f32x4 acc[4][2] = {};

  const int fr = lane & 15;
  const int q = lane >> 4;
  const int f7 = fr & 7;

  for (int k0 = 0; k0 < K; k0 += 64) {
#pragma unroll
    for (int i = 0; i < 4; ++i) {
      const int r0 = w * 32 + i * 8;
      gl_lds16(Ab + (size_t)r0 * lda + k0, &As[r0][0]);
    }
#pragma unroll
    for (int i = 0; i < 2; ++i) {
      const int r0 = w * 16 + i * 8;
      gl_lds16(Bb + (size_t)r0 * ldb + k0, &Bs[r0][0]);
    }
    __syncthreads();

    bf16x8 af[4][2], bf_[2][2];
#pragma unroll
    for (int kk = 0; kk < 2; ++kk) {
      const int sA = (((kk * 4 + q) ^ f7) << 3);
#pragma unroll
      for (int i = 0; i < 4; ++i)
        af[i][kk] = *reinterpret_cast<const bf16x8*>(
            &As[(w >> 1) * 64 + i * 16 + fr][sA]);
#pragma unroll
      for (int j = 0; j < 2; ++j)
        bf_[j][kk] = *reinterpret_cast<const bf16x8*>(
            &Bs[(w & 1) * 32 + j * 16 + fr][sA]);
    }
#pragma unroll
    for (int kk = 0; kk < 2; ++kk)
#pragma unroll
      for (int i = 0; i < 4; ++i)
#pragma unroll
        for (int j = 0; j < 2; ++j)
          acc[i][j] = __builtin_amdgcn_mfma_f32_16x16x32_bf16(
              af[i][kk], bf_[j][kk], acc[i][j], 0, 0, 0);
    __syncthreads();
  }

  const int crb = q * 4;
#pragma unroll
  for (int i = 0; i < 4; ++i) {
    size_t row = m0 + (w >> 1) * 64 + i * 16 + crb;
#pragma unroll
    for (int j = 0; j < 2; ++j) {
      size_t col = n0 + (w & 1) * 32 + j * 16 + fr;
#pragma unroll
      for (int r = 0; r < 4; ++r)
        C[(row + r) * ldc + col] = acc[i][j][r];
    }
  }
}

// ---------------------------------------------------------------------------
// Delta GEMM with fused bias+softplus epilogue, bf16 out.
// ---------------------------------------------------------------------------
__global__ __launch_bounds__(256) void gemm_delta(
    const unsigned short* __restrict__ A, const unsigned short* __restrict__ B,
    const float* __restrict__ bias, unsigned short* __restrict__ C, int K,
    int lda, int ldb, int ldc) {
  __shared__ __align__(16) unsigned short As[128][64];
  __shared__ __align__(16) unsigned short Bs[128][64];

  const int tid = threadIdx.x;
  const int lane = tid & 63;
  const int w = tid >> 6;

  const int gx = gridDim.x;
  const int nwg = gx * gridDim.y;
  const int id = blockIdx.y * gx + blockIdx.x;
  const int cpx = nwg >> 3;
  const int lt = (id & 7) * cpx + (id >> 3);
  const size_t m0 = (size_t)(lt / gx) * 128;
  const size_t n0 = (size_t)(lt % gx) * 128;

  const int rsub = lane >> 3;
  const int sslot = (lane & 7) ^ rsub;
  const unsigned short* Ab = A + m0 * lda + (size_t)rsub * lda + sslot * 8;
  const unsigned short* Bb = B + n0 * ldb + (size_t)rsub * ldb + sslot * 8;

  f32x4 acc[4][4] = {};

  const int fr = lane & 15;
  const int q = lane >> 4;
  const int f7 = fr & 7;

  for (int k0 = 0; k0 < K; k0 += 64) {
#pragma unroll
    for (int i = 0; i < 4; ++i) {
      const int r0 = w * 32 + i * 8;
      gl_lds16(Ab + (size_t)r0 * lda + k0, &As[r0][0]);
      gl_lds16(Bb + (size_t)r0 * ldb + k0, &Bs[r0][0]);
    }
    __syncthreads();

    bf16x8 af[4][2], bf_[4][2];
#pragma unroll
    for (int i = 0; i < 4; ++i) {
#pragma unroll
      for (int kk = 0; kk < 2; ++kk) {
        const int sA = (((kk * 4 + q) ^ f7) << 3);
        af[i][kk] = *reinterpret_cast<const bf16x8*>(
            &As[(w >> 1) * 64 + i * 16 + fr][sA]);
        bf_[i][kk] = *reinterpret_cast<const bf16x8*>(
            &Bs[(w & 1) * 64 + i * 16 + fr][sA]);
      }
    }
#pragma unroll
    for (int kk = 0; kk < 2; ++kk)
#pragma unroll
      for (int i = 0; i < 4; ++i)
#pragma unroll
        for (int j = 0; j < 4; ++j)
          acc[i][j] = __builtin_amdgcn_mfma_f32_16x16x32_bf16(
              af[i][kk], bf_[j][kk], acc[i][j], 0, 0, 0);
    __syncthreads();
  }

  const int crb = q * 4;
#pragma unroll
  for (int i = 0; i < 4; ++i) {
    size_t row = m0 + (w >> 1) * 64 + i * 16 + crb;
#pragma unroll
    for (int j = 0; j < 4; ++j) {
      size_t col = n0 + (w & 1) * 64 + j * 16 + fr;
      float bv = bias[col];
#pragma unroll
      for (int r = 0; r < 4; ++r)
        C[(row + r) * ldc + col] = f2bf(softplus_fast(acc[i][j][r] + bv));
    }
  }
}

// ---------------------------------------------------------------------------
// Skinny x_dbl GEMM: P[z][m][c] = sum_{k in z-chunk} u[m][k]*xpw[c][k].
// Split-K x8 (256 blocks -> 1/CU; was x4 = 128 blocks, half the GPU idle).
// ---------------------------------------------------------------------------
__global__ __launch_bounds__(256) void gemm_xdbl(
    const unsigned short* __restrict__ A,  // u bf16 [4096][2048]
    const unsigned short* __restrict__ B,  // xpw bf16 [96][2048]
    float* __restrict__ P) {               // partials [8][4096][96]
  __shared__ __align__(16) unsigned short As[128][64];
  __shared__ __align__(16) unsigned short Bs[96][64];

  const int tid = threadIdx.x;
  const int lane = tid & 63;
  const int w = tid >> 6;
  const size_t m0 = (size_t)blockIdx.x * 128;
  const int k0base = blockIdx.y * 256;

  const int rsub = lane >> 3;
  const int sslot = (lane & 7) ^ rsub;
  const unsigned short* Ab = A + m0 * DI + (size_t)rsub * DI + sslot * 8;
  const unsigned short* Bb = B + (size_t)rsub * DI + sslot * 8;

  f32x4 acc[4][3] = {};

  const int fr = lane & 15;
  const int q = lane >> 4;
  const int f7 = fr & 7;

  for (int ks = 0; ks < 4; ++ks) {
    const int k0 = k0base + ks * 64;
#pragma unroll
    for (int i = 0; i < 4; ++i) {
      const int r0 = w * 32 + i * 8;
      gl_lds16(Ab + (size_t)r0 * DI + k0, &As[r0][0]);
    }
#pragma unroll
    for (int i = 0; i < 3; ++i) {
      const int r0 = w * 24 + i * 8;
      gl_lds16(Bb + (size_t)r0 * DI + k0, &Bs[r0][0]);
    }
    __syncthreads();

    bf16x8 af[4][2], bf_[3][2];
#pragma unroll
    for (int kk = 0; kk < 2; ++kk) {
      const int sA = (((kk * 4 + q) ^ f7) << 3);
#pragma unroll
      for (int i = 0; i < 4; ++i)
        af[i][kk] = *reinterpret_cast<const bf16x8*>(
            &As[(w >> 1) * 64 + i * 16 + fr][sA]);
#pragma unroll
      for (int j = 0; j < 3; ++j)
        bf_[j][kk] = *reinterpret_cast<const bf16x8*>(
            &Bs[(w & 1) * 48 + j * 16 + fr][sA]);
    }
#pragma unroll
    for (int kk = 0; kk < 2; ++kk)
#pragma unroll
      for (int i = 0; i < 4; ++i)
#pragma unroll
        for (int j = 0; j < 3; ++j)
          acc[i][j] = __builtin_amdgcn_mfma_f32_16x16x32_bf16(
              af[i][kk], bf_[j][kk], acc[i][j], 0, 0, 0);
    __syncthreads();
  }

  float* Pz = P + (size_t)blockIdx.y * PN;
  const int crb = q * 4;
#pragma unroll
  for (int i = 0; i < 4; ++i) {
    size_t row = m0 + (w >> 1) * 64 + i * 16 + crb;
#pragma unroll
    for (int j = 0; j < 3; ++j) {
      int col = (w & 1) * 48 + j * 16 + fr;
#pragma unroll
      for (int r = 0; r < 4; ++r) Pz[(row + r) * XDR + col] = acc[i][j][r];
    }
  }
}

// reduce split-K partials (x8); emit dt bf16 (cols 0..63) + compact B/C f32.
__global__ __launch_bounds__(256) void reduce8x_kernel(
    const float* __restrict__ P, unsigned short* __restrict__ dtB,
    float* __restrict__ BC) {
  int i = blockIdx.x * 256 + threadIdx.x;  // < 4096*96
  int row = i / XDR, col = i - row * XDR;
  float s01 = P[i] + P[PN + i];
  float s23 = P[2 * PN + i] + P[3 * PN + i];
  float s45 = P[4 * PN + i] + P[5 * PN + i];
  float s67 = P[6 * PN + i] + P[7 * PN + i];
  float s = (s01 + s23) + (s45 + s67);
  if (col < 64)
    dtB[row * 64 + col] = f2bf(s);
  else
    BC[row * 32 + (col - 64)] = s;
}

// ---------------------------------------------------------------------------
// Depthwise causal conv (D_CONV=4) + bias + SiLU; bf16 in, bf16 out.
// 4 elems/thread (measured faster than 8/thread: TLP beats per-thread width
// in this latency-bound kernel — r33 regression).
// ---------------------------------------------------------------------------
__global__ __launch_bounds__(256) void conv_silu_kernel(
    const unsigned short* __restrict__ x, const float* __restrict__ w,
    const float* __restrict__ cb, unsigned short* __restrict__ out) {
  int idx = blockIdx.x * 256 + threadIdx.x;
  int e4 = idx % (DI / 4);
  int bl = idx / (DI / 4);
  int l = bl % LSEQ;
  int e = e4 * 4;

  const float4* cw = reinterpret_cast<const float4*>(w);
  float4 w0 = cw[e], w1 = cw[e + 1], w2 = cw[e + 2], w3 = cw[e + 3];
  float4 acc = *reinterpret_cast<const float4*>(&cb[e]);

#define TAPK(K, COMP)                                                       \
  {                                                                         \
    int ls = l - 3 + (K);                                                   \
    if (ls >= 0) {                                                          \
      uint2 xv = *reinterpret_cast<const uint2*>(                           \
          &x[((size_t)(bl) - 3 + (K)) * DI + e]);                           \
      acc.x = fmaf(bf2f((unsigned short)(xv.x & 0xffff)), w0.COMP, acc.x);  \
      acc.y = fmaf(bf2f((unsigned short)(xv.x >> 16)), w1.COMP, acc.y);     \
      acc.z = fmaf(bf2f((unsigned short)(xv.y & 0xffff)), w2.COMP, acc.z);  \
      acc.w = fmaf(bf2f((unsigned short)(xv.y >> 16)), w3.COMP, acc.w);     \
    }                                                                       \
  }
  TAPK(0, x)
  TAPK(1, y)
  TAPK(2, z)
  TAPK(3, w)
#undef TAPK

  acc.x = acc.x / (1.f + __expf(-acc.x));
  acc.y = acc.y / (1.f + __expf(-acc.y));
  acc.z = acc.z / (1.f + __expf(-acc.z));
  acc.w = acc.w / (1.f + __expf(-acc.w));
  *reinterpret_cast<uint2*>(&out[(size_t)bl * DI + e]) =
      make_uint2(pack2(acc.x, acc.y), pack2(acc.z, acc.w));
}

// ---------------------------------------------------------------------------
// Chunked selective scan, 16 states/thread (round-13 structure).
// aok check via 15 independent __expf.  passA fast path: P[n] = Q^(n+1).
// ---------------------------------------------------------------------------
__global__ __launch_bounds__(256) void scan_passA(
    const unsigned short* __restrict__ dB, const unsigned short* __restrict__ u,
    const float* __restrict__ bc, const float* __restrict__ A_log,
    float* __restrict__ sEnd, float* __restrict__ sProd) {
  int g = blockIdx.x * 256 + threadIdx.x;  // B*E*NC = 262144
  int e = g & (DI - 1);
  int c = (g >> 11) & (NC - 1);
  int b = g >> 17;

  const float nA0 = -__expf(A_log[e * DSTATE]);
  bool aok = true;
#pragma unroll
  for (int n = 1; n < DSTATE; ++n) {
    float nAn = -__expf(A_log[e * DSTATE + n]);
    aok = aok && (fabsf(nAn - (float)(n + 1) * nA0) <= 1e-4f * fabsf(nAn));
  }

  size_t off = ((size_t)b * LSEQ + c * TC) * DI + e;
  size_t boff = ((size_t)b * LSEQ + c * TC) * 32;

  float s[DSTATE], P[DSTATE];
#pragma unroll
  for (int n = 0; n < DSTATE; ++n) { s[n] = 0.f; P[n] = 1.f; }
  float sumd = 0.f;

  float d = bf2f(dB[off]);
  float ut = bf2f(u[off]);

  for (int t = 0; t < TC; ++t) {
    float d_n = 0.f, ut_n = 0.f;
    if (t + 1 < TC) {
      d_n = bf2f(dB[off + DI]);
      ut_n = bf2f(u[off + DI]);
    }

    float db = d * ut;
    float dA[DSTATE];
    if (aok) {
      pow_tree(__expf(d * nA0), dA);
      sumd += d;
    } else {
#pragma unroll
      for (int n = 0; n < DSTATE; ++n) {
        dA[n] = __expf(-d * __expf(A_log[e * DSTATE + n]));
        P[n] *= dA[n];
      }
    }
    const float4* bcp = reinterpret_cast<const float4*>(&bc[boff]);
    float4 B0 = bcp[0], B1 = bcp[1], B2 = bcp[2], B3 = bcp[3];
    float Bv[DSTATE] = {B0.x, B0.y, B0.z, B0.w, B1.x, B1.y, B1.z, B1.w,
                        B2.x, B2.y, B2.z, B2.w, B3.x, B3.y, B3.z, B3.w};
#pragma unroll
    for (int n = 0; n < DSTATE; ++n)
      s[n] = fmaf(s[n], dA[n], db * Bv[n]);
    off += DI;
    boff += 32;
    d = d_n; ut = ut_n;
  }

  if (aok) pow_tree(__expf(sumd * nA0), P);  // P[n] = Q^(n+1)

  size_t o = (((size_t)b * NC + c) * DI + e) * DSTATE;
  float4* se = reinterpret_cast<float4*>(&sEnd[o]);
  float4* sp = reinterpret_cast<float4*>(&sProd[o]);
  se[0] = make_float4(s[0], s[1], s[2], s[3]);
  se[1] = make_float4(s[4], s[5], s[6], s[7]);
  se[2] = make_float4(s[8], s[9], s[10], s[11]);
  se[3] = make_float4(s[12], s[13], s[14], s[15]);
  sp[0] = make_float4(P[0], P[1], P[2], P[3]);
  sp[1] = make_float4(P[4], P[5], P[6], P[7]);
  sp[2] = make_float4(P[8], P[9], P[10], P[11]);
  sp[3] = make_float4(P[12], P[13], P[14], P[15]);
}

// In-place: sEnd[o] is replaced by the chunk's INITIAL state.
__global__ __launch_bounds__(256) void scan_passB(
    float* __restrict__ sEnd, const float* __restrict__ sProd) {
  int g = blockIdx.x * 256 + threadIdx.x;  // 65,536
  int n = g & 15;
  int e = (g >> 4) & (DI - 1);
  int b = g >> 15;
  float s = 0.f;
  for (int c = 0; c < NC; ++c) {
    size_t o = (((size_t)b * NC + c) * DI + e) * DSTATE + n;
    float se = sEnd[o];
    float sp = sProd[o];
    sEnd[o] = s;
    s = fmaf(s, sp, se);
  }
}

__global__ __launch_bounds__(256) void scan_passC(
    const unsigned short* __restrict__ dB, const unsigned short* __restrict__ u,
    const unsigned short* __restrict__ z, const float* __restrict__ bc,
    const float* __restrict__ A_log, const float* __restrict__ Dv,
    const float* __restrict__ sInit, unsigned short* __restrict__ gOut) {
  int g = blockIdx.x * 256 + threadIdx.x;  // 262144
  int e = g & (DI - 1);
  int c = (g >> 11) & (NC - 1);
  int b = g >> 17;

  const float nA0 = -__expf(A_log[e * DSTATE]);
  bool aok = true;
#pragma unroll
  for (int n = 1; n < DSTATE; ++n) {
    float nAn = -__expf(A_log[e * DSTATE + n]);
    aok = aok && (fabsf(nAn - (float)(n + 1) * nA0) <= 1e-4f * fabsf(nAn));
  }
  const float Dval = Dv[e];

  size_t off = ((size_t)b * LSEQ + c * TC) * DI + e;
  size_t boff = ((size_t)b * LSEQ + c * TC) * 32;

  float s[DSTATE];
  {
    size_t o = (((size_t)b * NC + c) * DI + e) * DSTATE;
    const float4* si = reinterpret_cast<const float4*>(&sInit[o]);
    float4 s0 = si[0], s1 = si[1], s2 = si[2], s3 = si[3];
    s[0] = s0.x; s[1] = s0.y; s[2] = s0.z; s[3] = s0.w;
    s[4] = s1.x; s[5] = s1.y; s[6] = s1.z; s[7] = s1.w;
    s[8] = s2.x; s[9] = s2.y; s[10] = s2.z; s[11] = s2.w;
    s[12] = s3.x; s[13] = s3.y; s[14] = s3.z; s[15] = s3.w;
  }

  float d = bf2f(dB[off]);
  float ut = bf2f(u[off]);
  float zt = bf2f(z[off]);

  for (int t = 0; t < TC; ++t) {
    float d_n = 0.f, ut_n = 0.f, zt_n = 0.f;
    if (t + 1 < TC) {
      d_n = bf2f(dB[off + DI]);
      ut_n = bf2f(u[off + DI]);
      zt_n = bf2f(z[off + DI]);
    }

    float db = d * ut;
    float dA[DSTATE];
    if (aok) {
      pow_tree(__expf(d * nA0), dA);
    } else {
#pragma unroll
      for (int n = 0; n < DSTATE; ++n)
        dA[n] = __expf(-d * __expf(A_log[e * DSTATE + n]));
    }
    const float4* bcp = reinterpret_cast<const float4*>(&bc[boff]);
    float4 B0 = bcp[0], B1 = bcp[1], B2 = bcp[2], B3 = bcp[3];
    float4 C0 = bcp[4], C1 = bcp[5], C2 = bcp[6], C3 = bcp[7];
    float Bv[DSTATE] = {B0.x, B0.y, B0.z, B0.w, B1.x, B1.y, B1.z, B1.w,
                        B2.x, B2.y, B2.z, B2.w, B3.x, B3.y, B3.z, B3.w};
    float Cv[DSTATE] = {C0.x, C0.y, C0.z, C0.w, C1.x, C1.y, C1.z, C1.w,
                        C2.x, C2.y, C2.z, C2.w, C3.x, C3.y, C3.z, C3.w};
    float y0 = 0.f, y1 = 0.f, y2 = 0.f, y3 = 0.f;
#pragma unroll
    for (int n = 0; n < 4; ++n) {
      s[n] = fmaf(s[n], dA[n], db * Bv[n]);
      y0 = fmaf(s[n], Cv[n], y0);
      s[n + 4] = fmaf(s[n + 4], dA[n + 4], db * Bv[n + 4]);
      y1 = fmaf(s[n + 4], Cv[n + 4], y1);
      s[n + 8] = fmaf(s[n + 8], dA[n + 8], db * Bv[n + 8]);
      y2 = fmaf(s[n + 8], Cv[n + 8], y2);
      s[n + 12] = fmaf(s[n + 12], dA[n + 12], db * Bv[n + 12]);
      y3 = fmaf(s[n + 12], Cv[n + 12], y3);
    }
    float y = (y0 + y1) + (y2 + y3);
    float gate = zt / (1.f + __expf(-zt));
    gOut[off] = f2bf((y + Dval * ut) * gate);

    off += DI;
    boff += 32;
    d = d_n; ut = ut_n; zt = zt_n;
  }
}

// ---------------------------------------------------------------------------
extern "C" void kernel_launch(void* const* d_in, const int* in_sizes, int n_in,
                              void* d_out, int out_size, void* d_ws,
                              size_t ws_size, hipStream_t stream) {
  const float* hs = (const float*)d_in[0];
  const float* in2 = (const float*)d_in[1];
  const float* w1 = (const float*)d_in[2];
  const float* w2 = (const float*)d_in[3];
  const float* cw = (const float*)d_in[4];
  const float* cb = (const float*)d_in[5];
  const float* xpw = (const float*)d_in[6];
  const float* dtw = (const float*)d_in[7];
  const float* dtb = (const float*)d_in[8];
  const float* alog = (const float*)d_in[9];
  const float* Dv = (const float*)d_in[10];
  const float* ow = (const float*)d_in[11];
  float* out = (float*)d_out;

  const size_t BLE = (size_t)BATCH * LSEQ * DI;   // 8,388,608
  const size_t WN = (size_t)DI * DM;              // 2,097,152
  const size_t SC = (size_t)BATCH * NC * DI * DSTATE;  // 4,194,304

  // Regions (floats), all lifetimes disjoint:
  float* W = (float*)d_ws;
  float* bufX = W;             // BLE: xpreB (bf16, half) -> dB (bf16, half)
  float* M2 = W + BLE;         // BLE/2: hsb -> zb (bf16)
  float* M3 = M2 + BLE / 2;    // BLE/2: in2b -> ub (bf16)
  float* M4 = M3 + BLE / 2;    // BLE/2: wb1|wb2 -> xdblP(8PN)|dtB -> bufG
  float* sEnd = M4 + BLE / 2;  // SC (holds sInit after passB)
  float* sProd = sEnd + SC;    // SC
  float* BC = sProd + SC;      // 131,072 floats
  float* DED = BC + 131072;    // dedicated: owb | xpwB | dtwB

  unsigned short* xpreB = (unsigned short*)bufX;
  unsigned short* dB = (unsigned short*)bufX;
  unsigned short* hsb = (unsigned short*)M2;
  unsigned short* zb = (unsigned short*)M2;
  unsigned short* in2b = (unsigned short*)M3;
  unsigned short* ub = (unsigned short*)M3;
  unsigned short* wb1 = (unsigned short*)M4;
  unsigned short* wb2 = wb1 + WN;
  float* xdblP = M4;                                     // 8*PN floats
  unsigned short* dtB = (unsigned short*)(M4 + 8 * PN);  // 262,144 ushorts
  unsigned short* bufG = (unsigned short*)M4;            // after delta dead
  unsigned short* owb = (unsigned short*)DED;            // WN ushorts
  unsigned short* xpwB = owb + WN;                       // 196,608 ushorts
  unsigned short* dtwB = xpwB + XDR * DI;                // 131,072 ushorts

  const int M = BATCH * LSEQ;  // 4096
  dim3 blk(256);

  // 0. convert ALL bf16 operands in one launch
  cvt_all_kernel<<<G_OW / 256, blk, 0, stream>>>(hs, in2, w1, w2, xpw, dtw, ow,
                                                 hsb, in2b, wb1, wb2, xpwB,
                                                 dtwB, owb);
  // 1+2. x_pre = hs @ w1^T  AND  z = in2 @ w2^T (dual 4-phase 256^2 launch)
  gemm_in12<<<dim3(DI / 256, M / 256, 2), dim3(512), 0, stream>>>(
      hsb, wb1, xpreB, in2b, wb2, zb);
  // 3. u = silu(conv(x_pre) + cb)  (bf16 in/out)
  conv_silu_kernel<<<(M * (DI / 4)) / 256, blk, 0, stream>>>(xpreB, cw, cb,
                                                             ub);
  // 4. x_dbl partials = u @ xpw^T (split-K x8, 256 blocks) + reduce
  gemm_xdbl<<<dim3(M / 128, 8), blk, 0, stream>>>(ub, xpwB, xdblP);
  reduce8x_kernel<<<(M * XDR) / 256, blk, 0, stream>>>(xdblP, dtB, BC);
  // 5. d = softplus(dt @ dtw^T + dtb)  (bf16 out into bufX; xpreB dead)
  gemm_delta<<<dim3(DI / 128, M / 128), blk, 0, stream>>>(
      dtB, dtwB, dtb, dB, DTR, DTR, DTR, DI);
  // 6. chunked scan; passB in-place (sEnd -> sInit); passC emits g bf16
  scan_passA<<<(BATCH * DI * NC) / 256, blk, 0, stream>>>(dB, ub, BC, alog,
                                                          sEnd, sProd);
  scan_passB<<<(BATCH * DI * DSTATE) / 256, blk, 0, stream>>>(sEnd, sProd);
  scan_passC<<<(BATCH * DI * NC) / 256, blk, 0, stream>>>(
      dB, ub, zb, BC, alog, Dv, sEnd, bufG);
  // 7. out = g @ ow^T  (128x64 tile, 512 blocks)
  gemm_out<<<dim3(DM / 64, M / 128), blk, 0, stream>>>(bufG, owb, out);
}

// Round 36
// 214.807 us; speedup vs baseline: 1.0004x; 1.0004x over previous
//
#include <hip/hip_runtime.h>
#include <cstddef>
#include <cmath>

#define BATCH 2
#define LSEQ 2048
#define DM 1024
#define DSTATE 16
#define DI 2048
#define DTR 64
#define XDR 96   // DTR + 2*DSTATE
#define NC 64    // scan chunks
#define TC 32    // timesteps per chunk (NC*TC == LSEQ)
#define PN (4096 * 96)  // per-z x_dbl partial size

using f32x4 = __attribute__((ext_vector_type(4))) float;
using bf16x8 = __attribute__((ext_vector_type(8))) short;

__device__ __forceinline__ unsigned short f2bf(float f) {
  union { float f; unsigned int u; } c; c.f = f;
  unsigned int u = c.u;
  return (unsigned short)((u + 0x7FFFu + ((u >> 16) & 1u)) >> 16);  // RNE
}
__device__ __forceinline__ float bf2f(unsigned short h) {
  union { unsigned int u; float f; } c; c.u = ((unsigned int)h) << 16;
  return c.f;
}
__device__ __forceinline__ unsigned int pack2(float a, float b) {
  return (unsigned int)f2bf(a) | ((unsigned int)f2bf(b) << 16);
}

__device__ __forceinline__ void gl_lds16(const void* g, void* l) {
  __builtin_amdgcn_global_load_lds(
      (const __attribute__((address_space(1))) void*)g,
      (__attribute__((address_space(3))) void*)l, 16, 0, 0);
}

__device__ __forceinline__ float softplus_fast(float x) {
  float ex = __expf(x);
  return (x > 20.f) ? x : __logf(1.f + ex);
}

// dA[n] = q^(n+1), binary-power tree (depth ~4 instead of 15-serial).
__device__ __forceinline__ void pow_tree(float q1, float* dA) {
  float q2 = q1 * q1;
  float q3 = q2 * q1;
  float q4 = q2 * q2;
  float q8 = q4 * q4;
  float q5 = q4 * q1, q6 = q4 * q2, q7 = q4 * q3;
  dA[0] = q1;  dA[1] = q2;  dA[2] = q3;  dA[3] = q4;
  dA[4] = q5;  dA[5] = q6;  dA[6] = q7;  dA[7] = q8;
  dA[8] = q8 * q1;  dA[9] = q8 * q2;  dA[10] = q8 * q3;  dA[11] = q8 * q4;
  dA[12] = q8 * q5; dA[13] = q8 * q6; dA[14] = q8 * q7;  dA[15] = q8 * q8;
}

// ---------------------------------------------------------------------------
// Single-launch f32->bf16 conversion of ALL seven GEMM operands.
// ---------------------------------------------------------------------------
#define G_HS   524288            // BLM/8
#define G_IN2  (G_HS + 524288)
#define G_W1   (G_IN2 + 262144)  // WN/8
#define G_W2   (G_W1 + 262144)
#define G_XPW  (G_W2 + 24576)    // XDR*DI/8
#define G_DTW  (G_XPW + 16384)   // DI*DTR/8
#define G_OW   (G_DTW + 262144)  // total 1,875,968 -> 7328 blocks exactly

__global__ __launch_bounds__(256) void cvt_all_kernel(
    const float* __restrict__ hs, const float* __restrict__ in2,
    const float* __restrict__ w1, const float* __restrict__ w2,
    const float* __restrict__ xpw, const float* __restrict__ dtw,
    const float* __restrict__ ow, unsigned short* __restrict__ hsb,
    unsigned short* __restrict__ in2b, unsigned short* __restrict__ wb1,
    unsigned short* __restrict__ wb2, unsigned short* __restrict__ xpwB,
    unsigned short* __restrict__ dtwB, unsigned short* __restrict__ owb) {
  int i = blockIdx.x * 256 + threadIdx.x;
  const float* s;
  unsigned short* d;
  int k;
  if (i < G_HS)       { s = hs;  d = hsb;  k = i; }
  else if (i < G_IN2) { s = in2; d = in2b; k = i - G_HS; }
  else if (i < G_W1)  { s = w1;  d = wb1;  k = i - G_IN2; }
  else if (i < G_W2)  { s = w2;  d = wb2;  k = i - G_W1; }
  else if (i < G_XPW) { s = xpw; d = xpwB; k = i - G_W2; }
  else if (i < G_DTW) { s = dtw; d = dtwB; k = i - G_XPW; }
  else                { s = ow;  d = owb;  k = i - G_DTW; }
  const float4* sp = reinterpret_cast<const float4*>(s) + (size_t)k * 2;
  float4 a = sp[0], b = sp[1];
  uint4 v = make_uint4(pack2(a.x, a.y), pack2(a.z, a.w), pack2(b.x, b.y),
                       pack2(b.z, b.w));
  *(reinterpret_cast<uint4*>(d) + k) = v;
}

// ---------------------------------------------------------------------------
// Dual in-proj GEMM, 4-phase 256^2 counted-vmcnt schedule.
// BM=BN=256, BK=64, 8 waves (2M x 4N), 512 threads, 128 KiB LDS (2 K-tile
// double buffer).  Per phase: one A-half (4 m-frags) x K=64 = 32 MFMA.
// Stage schedule (target freed by an earlier phase-end barrier):
//   phA: T+1.A -> buf1.A (freed prev phD)   phB: T+2.B -> buf0.B (phA)
//   phC: T+2.A -> buf0.A (phB)              phD: T+3.B -> buf1.B (phC)
// vmcnt(4) at phB/phD (4 loads = 1 tile stay in flight, never 0 in loop).
// ---------------------------------------------------------------------------
__global__ __launch_bounds__(512) void gemm_in12(
    const unsigned short* __restrict__ A0, const unsigned short* __restrict__ B0,
    unsigned short* __restrict__ C0, const unsigned short* __restrict__ A1,
    const unsigned short* __restrict__ B1, unsigned short* __restrict__ C1) {
  __shared__ __align__(16) unsigned short Asm[2][256][64];  // 64 KiB
  __shared__ __align__(16) unsigned short Bsm[2][256][64];  // 64 KiB

  const unsigned short* A = blockIdx.z ? A1 : A0;
  const unsigned short* B = blockIdx.z ? B1 : B0;
  unsigned short* C = blockIdx.z ? C1 : C0;
  const int lda = DM, ldc = DI;  // K = DM = 1024 -> 16 K-tiles of 64

  const int tid = threadIdx.x;
  const int lane = tid & 63;
  const int w = tid >> 6;   // 0..7
  const int wr = w >> 2;    // 0..1  (M half)
  const int wn = w & 3;     // 0..3  (N quarter)

  const int gx = gridDim.x;            // 8
  const int nwg = gx * gridDim.y;      // 128 (per z)
  const int id = blockIdx.y * gx + blockIdx.x;
  const int cpx = nwg >> 3;
  const int lt = (id & 7) * cpx + (id >> 3);
  const size_t m0 = (size_t)(lt / gx) * 256;
  const size_t n0 = (size_t)(lt % gx) * 256;

  const int rsub = lane >> 3;
  const int sslot = (lane & 7) ^ rsub;
  const unsigned short* Ab = A + (m0 + (size_t)rsub) * lda + sslot * 8;
  const unsigned short* Bb = B + (n0 + (size_t)rsub) * lda + sslot * 8;

  const int fr = lane & 15;
  const int q = lane >> 4;
  const int f7 = fr & 7;

  f32x4 acc[8][4] = {};
  bf16x8 bfr[4][2];

// stage a full 256x64 tile of K-tile T: each wave fills 32 rows (4 gl_lds)
#define STA(BUF, T)                                                         \
  {                                                                         \
    const int r0_ = w * 32;                                                 \
    const unsigned short* s_ = Ab + (size_t)r0_ * lda + (T) * 64;           \
    gl_lds16(s_, &Asm[BUF][r0_][0]);                                        \
    gl_lds16(s_ + (size_t)8 * lda, &Asm[BUF][r0_ + 8][0]);                  \
    gl_lds16(s_ + (size_t)16 * lda, &Asm[BUF][r0_ + 16][0]);                \
    gl_lds16(s_ + (size_t)24 * lda, &Asm[BUF][r0_ + 24][0]);                \
  }
#define STB(BUF, T)                                                         \
  {                                                                         \
    const int r0_ = w * 32;                                                 \
    const unsigned short* s_ = Bb + (size_t)r0_ * lda + (T) * 64;           \
    gl_lds16(s_, &Bsm[BUF][r0_][0]);                                        \
    gl_lds16(s_ + (size_t)8 * lda, &Bsm[BUF][r0_ + 8][0]);                  \
    gl_lds16(s_ + (size_t)16 * lda, &Bsm[BUF][r0_ + 16][0]);                \
    gl_lds16(s_ + (size_t)24 * lda, &Bsm[BUF][r0_ + 24][0]);                \
  }

// one phase: ds-load half subtile | stage | [vmcnt] | barrier | lgkm0 | MFMA
#define PH4(BUFI, HALF, LOADB, STG, VM)                                     \
  {                                                                         \
    if (LOADB) {                                                            \
      _Pragma("unroll") for (int j = 0; j < 4; ++j)                         \
          _Pragma("unroll") for (int kk = 0; kk < 2; ++kk)                  \
              bfr[j][kk] = *reinterpret_cast<const bf16x8*>(                \
                  &Bsm[BUFI][wn * 64 + j * 16 + fr]                         \
                      [((kk * 4 + q) ^ f7) << 3]);                          \
    }                                                                       \
    bf16x8 af_[4][2];                                                       \
    _Pragma("unroll") for (int mi = 0; mi < 4; ++mi)                        \
        _Pragma("unroll") for (int kk = 0; kk < 2; ++kk)                    \
            af_[mi][kk] = *reinterpret_cast<const bf16x8*>(                 \
                &Asm[BUFI][wr * 128 + ((HALF)*4 + mi) * 16 + fr]            \
                    [((kk * 4 + q) ^ f7) << 3]);                            \
    STG;                                                                    \
    VM;                                                                     \
    __builtin_amdgcn_s_barrier();                                           \
    asm volatile("s_waitcnt lgkmcnt(0)" ::: "memory");                      \
    __builtin_amdgcn_sched_barrier(0);                                      \
    __builtin_amdgcn_s_setprio(1);                                          \
    _Pragma("unroll") for (int kk = 0; kk < 2; ++kk)                        \
        _Pragma("unroll") for (int mi = 0; mi < 4; ++mi)                    \
            _Pragma("unroll") for (int j = 0; j < 4; ++j)                   \
                acc[(HALF)*4 + mi][j] =                                     \
                    __builtin_amdgcn_mfma_f32_16x16x32_bf16(                \
                        af_[mi][kk], bfr[j][kk], acc[(HALF)*4 + mi][j],     \
                        0, 0, 0);                                           \
    __builtin_amdgcn_s_setprio(0);                                          \
    __builtin_amdgcn_s_barrier();                                           \
  }

#define VMC4_ asm volatile("s_waitcnt vmcnt(4)" ::: "memory")
#define VMC0_ asm volatile("s_waitcnt vmcnt(0)" ::: "memory")
#define NOPS_ ((void)0)

  // prologue: T0.B, T0.A, T1.B; drain T0 (T1.B stays in flight)
  STB(0, 0)
  STA(0, 0)
  STB(1, 1)
  VMC4_;
  __builtin_amdgcn_s_barrier();

#pragma unroll 1
  for (int it = 0; it < 7; ++it) {
    const int t0 = 2 * it, t1 = 2 * it + 1;
    PH4(0, 0, true,  STA(1, t1),     NOPS_)   // phA
    PH4(0, 1, false, STB(0, t0 + 2), VMC4_)   // phB: drain T+1.A (+lingering)
    PH4(1, 0, true,  STA(0, t0 + 2), NOPS_)   // phC
    PH4(1, 1, false, STB(1, t1 + 2), VMC4_)   // phD: drain T+2.B + T+2.A
  }
  // final iteration: tiles 14 (buf0), 15 (buf1); no further staging
  PH4(0, 0, true,  STA(1, 15), NOPS_)
  PH4(0, 1, false, NOPS_,      VMC0_)
  PH4(1, 0, true,  NOPS_, NOPS_)
  PH4(1, 1, false, NOPS_, NOPS_)

#undef STA
#undef STB
#undef PH4

  const int crb = q * 4;
#pragma unroll
  for (int mf = 0; mf < 8; ++mf) {
    size_t row = m0 + wr * 128 + mf * 16 + crb;
#pragma unroll
    for (int j = 0; j < 4; ++j) {
      size_t col = n0 + wn * 64 + j * 16 + fr;
#pragma unroll
      for (int r = 0; r < 4; ++r)
        C[(row + r) * ldc + col] = f2bf(acc[mf][j][r]);
    }
  }
}

// ---------------------------------------------------------------------------
// Out-proj GEMM: out[m,n] = sum_k g[m,k]*ow[n,k].  M=4096, N=DM, K=DI.
// BM=256, BN=64 (256 blocks = 1/CU), 8 waves (4M x 2N), wave tile 64x32.
// 2-buffer counted-vmcnt schedule, one phase per K-tile (16 MFMA):
//   ds_read frags -> lgkm0 -> barrier1 (reads done) -> stage T+2 into the
//   just-freed buffer -> vmcnt(5) (T+1's 5 loads drained; T+2's in flight)
//   -> barrier2 -> MFMA.  f32 out.
// ---------------------------------------------------------------------------
__global__ __launch_bounds__(512) void gemm_out(
    const unsigned short* __restrict__ A, const unsigned short* __restrict__ B,
    float* __restrict__ C) {
  __shared__ __align__(16) unsigned short Asm[2][256][64];  // 64 KiB
  __shared__ __align__(16) unsigned short Bsm[2][64][64];   // 16 KiB

  const int lda = DI, ldc = DM;  // K = DI = 2048 -> 32 K-tiles of 64

  const int tid = threadIdx.x;
  const int lane = tid & 63;
  const int w = tid >> 6;    // 0..7
  const int wm = w >> 1;     // 0..3 (M quarter)
  const int wn = w & 1;      // 0..1 (N half)

  const int gx = gridDim.x;        // 16 (N tiles)
  const int nwg = gx * gridDim.y;  // 256
  const int id = blockIdx.y * gx + blockIdx.x;
  const int cpx = nwg >> 3;
  const int lt = (id & 7) * cpx + (id >> 3);
  const size_t m0 = (size_t)(lt / gx) * 256;
  const size_t n0 = (size_t)(lt % gx) * 64;

  const int rsub = lane >> 3;
  const int sslot = (lane & 7) ^ rsub;
  const unsigned short* Ab = A + (m0 + (size_t)rsub) * lda + sslot * 8;
  const unsigned short* Bb = B + (n0 + (size_t)rsub) * lda + sslot * 8;

  const int fr = lane & 15;
  const int q = lane >> 4;
  const int f7 = fr & 7;

  f32x4 acc[4][2] = {};

// stage A 256x64 tile (4 gl_lds/wave) and B 64x64 tile (1 gl_lds/wave)
#define OSTA(BUF, T)                                                        \
  {                                                                         \
    const int r0_ = w * 32;                                                 \
    const unsigned short* s_ = Ab + (size_t)r0_ * lda + (T) * 64;           \
    gl_lds16(s_, &Asm[BUF][r0_][0]);                                        \
    gl_lds16(s_ + (size_t)8 * lda, &Asm[BUF][r0_ + 8][0]);                  \
    gl_lds16(s_ + (size_t)16 * lda, &Asm[BUF][r0_ + 16][0]);                \
    gl_lds16(s_ + (size_t)24 * lda, &Asm[BUF][r0_ + 24][0]);                \
  }
#define OSTB(BUF, T)                                                        \
  {                                                                         \
    const int r0_ = w * 8;                                                  \
    gl_lds16(Bb + (size_t)r0_ * lda + (T) * 64, &Bsm[BUF][r0_][0]);         \
  }

// one phase = one K-tile (16 MFMA); stage overwrites the SAME buffer after
// barrier1 confirms all reads retired.
#define OPH(BUFI, STG, VM)                                                  \
  {                                                                         \
    bf16x8 af_[4][2], bf_[2][2];                                            \
    _Pragma("unroll") for (int j = 0; j < 2; ++j)                           \
        _Pragma("unroll") for (int kk = 0; kk < 2; ++kk)                    \
            bf_[j][kk] = *reinterpret_cast<const bf16x8*>(                  \
                &Bsm[BUFI][wn * 32 + j * 16 + fr]                           \
                    [((kk * 4 + q) ^ f7) << 3]);                            \
    _Pragma("unroll") for (int mi = 0; mi < 4; ++mi)                        \
        _Pragma("unroll") for (int kk = 0; kk < 2; ++kk)                    \
            af_[mi][kk] = *reinterpret_cast<const bf16x8*>(                 \
                &Asm[BUFI][wm * 64 + mi * 16 + fr]                          \
                    [((kk * 4 + q) ^ f7) << 3]);                            \
    asm volatile("s_waitcnt lgkmcnt(0)" ::: "memory");                      \
    __builtin_amdgcn_sched_barrier(0);                                      \
    __builtin_amdgcn_s_barrier();                                           \
    STG;                                                                    \
    VM;                                                                     \
    __builtin_amdgcn_s_barrier();                                           \
    __builtin_amdgcn_s_setprio(1);                                          \
    _Pragma("unroll") for (int kk = 0; kk < 2; ++kk)                        \
        _Pragma("unroll") for (int mi = 0; mi < 4; ++mi)                    \
            _Pragma("unroll") for (int j = 0; j < 2; ++j)                   \
                acc[mi][j] = __builtin_amdgcn_mfma_f32_16x16x32_bf16(       \
                    af_[mi][kk], bf_[j][kk], acc[mi][j], 0, 0, 0);          \
    __builtin_amdgcn_s_setprio(0);                                          \
  }

#define OVMC5_ asm volatile("s_waitcnt vmcnt(5)" ::: "memory")
#define OVMC0_ asm volatile("s_waitcnt vmcnt(0)" ::: "memory")
#define ONOP_ ((void)0)

  // prologue: stage T0 -> buf0, T1 -> buf1; drain T0 (T1's 5 in flight)
  OSTA(0, 0) OSTB(0, 0)
  OSTA(1, 1) OSTB(1, 1)
  OVMC5_;
  __builtin_amdgcn_s_barrier();

#pragma unroll 1
  for (int it = 0; it < 15; ++it) {
    const int t0 = 2 * it, t1 = 2 * it + 1;
    OPH(0, { OSTA(0, t0 + 2) OSTB(0, t0 + 2) }, OVMC5_)  // tile t0
    OPH(1, { OSTA(1, t1 + 2) OSTB(1, t1 + 2) }, OVMC5_)  // tile t1
  }
  // tiles 30 (buf0) and 31 (buf1); no further staging
  OPH(0, ONOP_, OVMC0_)
  OPH(1, ONOP_, ONOP_)

#undef OSTA
#undef OSTB
#undef OPH

  const int crb = q * 4;
#pragma unroll
  for (int mf = 0; mf < 4; ++mf) {
    size_t row = m0 + wm * 64 + mf * 16 + crb;
#pragma unroll
    for (int j = 0; j < 2; ++j) {
      size_t col = n0 + wn * 32 + j * 16 + fr;
#pragma unroll
      for (int r = 0; r < 4; ++r)
        C[(row + r) * ldc + col] = acc[mf][j][r];
    }
  }
}

// ---------------------------------------------------------------------------
// Delta GEMM with fused bias+softplus epilogue, bf16 out.
// ---------------------------------------------------------------------------
__global__ __launch_bounds__(256) void gemm_delta(
    const unsigned short* __restrict__ A, const unsigned short* __restrict__ B,
    const float* __restrict__ bias, unsigned short* __restrict__ C, int K,
    int lda, int ldb, int ldc) {
  __shared__ __align__(16) unsigned short As[128][64];
  __shared__ __align__(16) unsigned short Bs[128][64];

  const int tid = threadIdx.x;
  const int lane = tid & 63;
  const int w = tid >> 6;

  const int gx = gridDim.x;
  const int nwg = gx * gridDim.y;
  const int id = blockIdx.y * gx + blockIdx.x;
  const int cpx = nwg >> 3;
  const int lt = (id & 7) * cpx + (id >> 3);
  const size_t m0 = (size_t)(lt / gx) * 128;
  const size_t n0 = (size_t)(lt % gx) * 128;

  const int rsub = lane >> 3;
  const int sslot = (lane & 7) ^ rsub;
  const unsigned short* Ab = A + m0 * lda + (size_t)rsub * lda + sslot * 8;
  const unsigned short* Bb = B + n0 * ldb + (size_t)rsub * ldb + sslot * 8;

  f32x4 acc[4][4] = {};

  const int fr = lane & 15;
  const int q = lane >> 4;
  const int f7 = fr & 7;

  for (int k0 = 0; k0 < K; k0 += 64) {
#pragma unroll
    for (int i = 0; i < 4; ++i) {
      const int r0 = w * 32 + i * 8;
      gl_lds16(Ab + (size_t)r0 * lda + k0, &As[r0][0]);
      gl_lds16(Bb + (size_t)r0 * ldb + k0, &Bs[r0][0]);
    }
    __syncthreads();

    bf16x8 af[4][2], bf_[4][2];
#pragma unroll
    for (int i = 0; i < 4; ++i) {
#pragma unroll
      for (int kk = 0; kk < 2; ++kk) {
        const int sA = (((kk * 4 + q) ^ f7) << 3);
        af[i][kk] = *reinterpret_cast<const bf16x8*>(
            &As[(w >> 1) * 64 + i * 16 + fr][sA]);
        bf_[i][kk] = *reinterpret_cast<const bf16x8*>(
            &Bs[(w & 1) * 64 + i * 16 + fr][sA]);
      }
    }
#pragma unroll
    for (int kk = 0; kk < 2; ++kk)
#pragma unroll
      for (int i = 0; i < 4; ++i)
#pragma unroll
        for (int j = 0; j < 4; ++j)
          acc[i][j] = __builtin_amdgcn_mfma_f32_16x16x32_bf16(
              af[i][kk], bf_[j][kk], acc[i][j], 0, 0, 0);
    __syncthreads();
  }

  const int crb = q * 4;
#pragma unroll
  for (int i = 0; i < 4; ++i) {
    size_t row = m0 + (w >> 1) * 64 + i * 16 + crb;
#pragma unroll
    for (int j = 0; j < 4; ++j) {
      size_t col = n0 + (w & 1) * 64 + j * 16 + fr;
      float bv = bias[col];
#pragma unroll
      for (int r = 0; r < 4; ++r)
        C[(row + r) * ldc + col] = f2bf(softplus_fast(acc[i][j][r] + bv));
    }
  }
}

// ---------------------------------------------------------------------------
// Skinny x_dbl GEMM: P[z][m][c] = sum_{k in z-chunk} u[m][k]*xpw[c][k].
// Split-K x8 (256 blocks -> 1/CU).
// ---------------------------------------------------------------------------
__global__ __launch_bounds__(256) void gemm_xdbl(
    const unsigned short* __restrict__ A,  // u bf16 [4096][2048]
    const unsigned short* __restrict__ B,  // xpw bf16 [96][2048]
    float* __restrict__ P) {               // partials [8][4096][96]
  __shared__ __align__(16) unsigned short As[128][64];
  __shared__ __align__(16) unsigned short Bs[96][64];

  const int tid = threadIdx.x;
  const int lane = tid & 63;
  const int w = tid >> 6;
  const size_t m0 = (size_t)blockIdx.x * 128;
  const int k0base = blockIdx.y * 256;

  const int rsub = lane >> 3;
  const int sslot = (lane & 7) ^ rsub;
  const unsigned short* Ab = A + m0 * DI + (size_t)rsub * DI + sslot * 8;
  const unsigned short* Bb = B + (size_t)rsub * DI + sslot * 8;

  f32x4 acc[4][3] = {};

  const int fr = lane & 15;
  const int q = lane >> 4;
  const int f7 = fr & 7;

  for (int ks = 0; ks < 4; ++ks) {
    const int k0 = k0base + ks * 64;
#pragma unroll
    for (int i = 0; i < 4; ++i) {
      const int r0 = w * 32 + i * 8;
      gl_lds16(Ab + (size_t)r0 * DI + k0, &As[r0][0]);
    }
#pragma unroll
    for (int i = 0; i < 3; ++i) {
      const int r0 = w * 24 + i * 8;
      gl_lds16(Bb + (size_t)r0 * DI + k0, &Bs[r0][0]);
    }
    __syncthreads();

    bf16x8 af[4][2], bf_[3][2];
#pragma unroll
    for (int kk = 0; kk < 2; ++kk) {
      const int sA = (((kk * 4 + q) ^ f7) << 3);
#pragma unroll
      for (int i = 0; i < 4; ++i)
        af[i][kk] = *reinterpret_cast<const bf16x8*>(
            &As[(w >> 1) * 64 + i * 16 + fr][sA]);
#pragma unroll
      for (int j = 0; j < 3; ++j)
        bf_[j][kk] = *reinterpret_cast<const bf16x8*>(
            &Bs[(w & 1) * 48 + j * 16 + fr][sA]);
    }
#pragma unroll
    for (int kk = 0; kk < 2; ++kk)
#pragma unroll
      for (int i = 0; i < 4; ++i)
#pragma unroll
        for (int j = 0; j < 3; ++j)
          acc[i][j] = __builtin_amdgcn_mfma_f32_16x16x32_bf16(
              af[i][kk], bf_[j][kk], acc[i][j], 0, 0, 0);
    __syncthreads();
  }

  float* Pz = P + (size_t)blockIdx.y * PN;
  const int crb = q * 4;
#pragma unroll
  for (int i = 0; i < 4; ++i) {
    size_t row = m0 + (w >> 1) * 64 + i * 16 + crb;
#pragma unroll
    for (int j = 0; j < 3; ++j) {
      int col = (w & 1) * 48 + j * 16 + fr;
#pragma unroll
      for (int r = 0; r < 4; ++r) Pz[(row + r) * XDR + col] = acc[i][j][r];
    }
  }
}

// reduce split-K partials (x8); emit dt bf16 (cols 0..63) + compact B/C f32.
__global__ __launch_bounds__(256) void reduce8x_kernel(
    const float* __restrict__ P, unsigned short* __restrict__ dtB,
    float* __restrict__ BC) {
  int i = blockIdx.x * 256 + threadIdx.x;  // < 4096*96
  int row = i / XDR, col = i - row * XDR;
  float s01 = P[i] + P[PN + i];
  float s23 = P[2 * PN + i] + P[3 * PN + i];
  float s45 = P[4 * PN + i] + P[5 * PN + i];
  float s67 = P[6 * PN + i] + P[7 * PN + i];
  float s = (s01 + s23) + (s45 + s67);
  if (col < 64)
    dtB[row * 64 + col] = f2bf(s);
  else
    BC[row * 32 + (col - 64)] = s;
}

// ---------------------------------------------------------------------------
// Depthwise causal conv (D_CONV=4) + bias + SiLU; bf16 in, bf16 out.
// 4 elems/thread (measured faster than 8/thread — r33 regression).
// ---------------------------------------------------------------------------
__global__ __launch_bounds__(256) void conv_silu_kernel(
    const unsigned short* __restrict__ x, const float* __restrict__ w,
    const float* __restrict__ cb, unsigned short* __restrict__ out) {
  int idx = blockIdx.x * 256 + threadIdx.x;
  int e4 = idx % (DI / 4);
  int bl = idx / (DI / 4);
  int l = bl % LSEQ;
  int e = e4 * 4;

  const float4* cw = reinterpret_cast<const float4*>(w);
  float4 w0 = cw[e], w1 = cw[e + 1], w2 = cw[e + 2], w3 = cw[e + 3];
  float4 acc = *reinterpret_cast<const float4*>(&cb[e]);

#define TAPK(K, COMP)                                                       \
  {                                                                         \
    int ls = l - 3 + (K);                                                   \
    if (ls >= 0) {                                                          \
      uint2 xv = *reinterpret_cast<const uint2*>(                           \
          &x[((size_t)(bl) - 3 + (K)) * DI + e]);                           \
      acc.x = fmaf(bf2f((unsigned short)(xv.x & 0xffff)), w0.COMP, acc.x);  \
      acc.y = fmaf(bf2f((unsigned short)(xv.x >> 16)), w1.COMP, acc.y);     \
      acc.z = fmaf(bf2f((unsigned short)(xv.y & 0xffff)), w2.COMP, acc.z);  \
      acc.w = fmaf(bf2f((unsigned short)(xv.y >> 16)), w3.COMP, acc.w);     \
    }                                                                       \
  }
  TAPK(0, x)
  TAPK(1, y)
  TAPK(2, z)
  TAPK(3, w)
#undef TAPK

  acc.x = acc.x / (1.f + __expf(-acc.x));
  acc.y = acc.y / (1.f + __expf(-acc.y));
  acc.z = acc.z / (1.f + __expf(-acc.z));
  acc.w = acc.w / (1.f + __expf(-acc.w));
  *reinterpret_cast<uint2*>(&out[(size_t)bl * DI + e]) =
      make_uint2(pack2(acc.x, acc.y), pack2(acc.z, acc.w));
}

// ---------------------------------------------------------------------------
// Chunked selective scan, 16 states/thread (round-13 structure).
// aok check via 15 independent __expf.  passA fast path: P[n] = Q^(n+1).
// ---------------------------------------------------------------------------
__global__ __launch_bounds__(256) void scan_passA(
    const unsigned short* __restrict__ dB, const unsigned short* __restrict__ u,
    const float* __restrict__ bc, const float* __restrict__ A_log,
    float* __restrict__ sEnd, float* __restrict__ sProd) {
  int g = blockIdx.x * 256 + threadIdx.x;  // B*E*NC = 262144
  int e = g & (DI - 1);
  int c = (g >> 11) & (NC - 1);
  int b = g >> 17;

  const float nA0 = -__expf(A_log[e * DSTATE]);
  bool aok = true;
#pragma unroll
  for (int n = 1; n < DSTATE; ++n) {
    float nAn = -__expf(A_log[e * DSTATE + n]);
    aok = aok && (fabsf(nAn - (float)(n + 1) * nA0) <= 1e-4f * fabsf(nAn));
  }

  size_t off = ((size_t)b * LSEQ + c * TC) * DI + e;
  size_t boff = ((size_t)b * LSEQ + c * TC) * 32;

  float s[DSTATE], P[DSTATE];
#pragma unroll
  for (int n = 0; n < DSTATE; ++n) { s[n] = 0.f; P[n] = 1.f; }
  float sumd = 0.f;

  float d = bf2f(dB[off]);
  float ut = bf2f(u[off]);

  for (int t = 0; t < TC; ++t) {
    float d_n = 0.f, ut_n = 0.f;
    if (t + 1 < TC) {
      d_n = bf2f(dB[off + DI]);
      ut_n = bf2f(u[off + DI]);
    }

    float db = d * ut;
    float dA[DSTATE];
    if (aok) {
      pow_tree(__expf(d * nA0), dA);
      sumd += d;
    } else {
#pragma unroll
      for (int n = 0; n < DSTATE; ++n) {
        dA[n] = __expf(-d * __expf(A_log[e * DSTATE + n]));
        P[n] *= dA[n];
      }
    }
    const float4* bcp = reinterpret_cast<const float4*>(&bc[boff]);
    float4 B0 = bcp[0], B1 = bcp[1], B2 = bcp[2], B3 = bcp[3];
    float Bv[DSTATE] = {B0.x, B0.y, B0.z, B0.w, B1.x, B1.y, B1.z, B1.w,
                        B2.x, B2.y, B2.z, B2.w, B3.x, B3.y, B3.z, B3.w};
#pragma unroll
    for (int n = 0; n < DSTATE; ++n)
      s[n] = fmaf(s[n], dA[n], db * Bv[n]);
    off += DI;
    boff += 32;
    d = d_n; ut = ut_n;
  }

  if (aok) pow_tree(__expf(sumd * nA0), P);  // P[n] = Q^(n+1)

  size_t o = (((size_t)b * NC + c) * DI + e) * DSTATE;
  float4* se = reinterpret_cast<float4*>(&sEnd[o]);
  float4* sp = reinterpret_cast<float4*>(&sProd[o]);
  se[0] = make_float4(s[0], s[1], s[2], s[3]);
  se[1] = make_float4(s[4], s[5], s[6], s[7]);
  se[2] = make_float4(s[8], s[9], s[10], s[11]);
  se[3] = make_float4(s[12], s[13], s[14], s[15]);
  sp[0] = make_float4(P[0], P[1], P[2], P[3]);
  sp[1] = make_float4(P[4], P[5], P[6], P[7]);
  sp[2] = make_float4(P[8], P[9], P[10], P[11]);
  sp[3] = make_float4(P[12], P[13], P[14], P[15]);
}

// In-place: sEnd[o] is replaced by the chunk's INITIAL state.
__global__ __launch_bounds__(256) void scan_passB(
    float* __restrict__ sEnd, const float* __restrict__ sProd) {
  int g = blockIdx.x * 256 + threadIdx.x;  // 65,536
  int n = g & 15;
  int e = (g >> 4) & (DI - 1);
  int b = g >> 15;
  float s = 0.f;
  for (int c = 0; c < NC; ++c) {
    size_t o = (((size_t)b * NC + c) * DI + e) * DSTATE + n;
    float se = sEnd[o];
    float sp = sProd[o];
    sEnd[o] = s;
    s = fmaf(s, sp, se);
  }
}

__global__ __launch_bounds__(256) void scan_passC(
    const unsigned short* __restrict__ dB, const unsigned short* __restrict__ u,
    const unsigned short* __restrict__ z, const float* __restrict__ bc,
    const float* __restrict__ A_log, const float* __restrict__ Dv,
    const float* __restrict__ sInit, unsigned short* __restrict__ gOut) {
  int g = blockIdx.x * 256 + threadIdx.x;  // 262144
  int e = g & (DI - 1);
  int c = (g >> 11) & (NC - 1);
  int b = g >> 17;

  const float nA0 = -__expf(A_log[e * DSTATE]);
  bool aok = true;
#pragma unroll
  for (int n = 1; n < DSTATE; ++n) {
    float nAn = -__expf(A_log[e * DSTATE + n]);
    aok = aok && (fabsf(nAn - (float)(n + 1) * nA0) <= 1e-4f * fabsf(nAn));
  }
  const float Dval = Dv[e];

  size_t off = ((size_t)b * LSEQ + c * TC) * DI + e;
  size_t boff = ((size_t)b * LSEQ + c * TC) * 32;

  float s[DSTATE];
  {
    size_t o = (((size_t)b * NC + c) * DI + e) * DSTATE;
    const float4* si = reinterpret_cast<const float4*>(&sInit[o]);
    float4 s0 = si[0], s1 = si[1], s2 = si[2], s3 = si[3];
    s[0] = s0.x; s[1] = s0.y; s[2] = s0.z; s[3] = s0.w;
    s[4] = s1.x; s[5] = s1.y; s[6] = s1.z; s[7] = s1.w;
    s[8] = s2.x; s[9] = s2.y; s[10] = s2.z; s[11] = s2.w;
    s[12] = s3.x; s[13] = s3.y; s[14] = s3.z; s[15] = s3.w;
  }

  float d = bf2f(dB[off]);
  float ut = bf2f(u[off]);
  float zt = bf2f(z[off]);

  for (int t = 0; t < TC; ++t) {
    float d_n = 0.f, ut_n = 0.f, zt_n = 0.f;
    if (t + 1 < TC) {
      d_n = bf2f(dB[off + DI]);
      ut_n = bf2f(u[off + DI]);
      zt_n = bf2f(z[off + DI]);
    }

    float db = d * ut;
    float dA[DSTATE];
    if (aok) {
      pow_tree(__expf(d * nA0), dA);
    } else {
#pragma unroll
      for (int n = 0; n < DSTATE; ++n)
        dA[n] = __expf(-d * __expf(A_log[e * DSTATE + n]));
    }
    const float4* bcp = reinterpret_cast<const float4*>(&bc[boff]);
    float4 B0 = bcp[0], B1 = bcp[1], B2 = bcp[2], B3 = bcp[3];
    float4 C0 = bcp[4], C1 = bcp[5], C2 = bcp[6], C3 = bcp[7];
    float Bv[DSTATE] = {B0.x, B0.y, B0.z, B0.w, B1.x, B1.y, B1.z, B1.w,
                        B2.x, B2.y, B2.z, B2.w, B3.x, B3.y, B3.z, B3.w};
    float Cv[DSTATE] = {C0.x, C0.y, C0.z, C0.w, C1.x, C1.y, C1.z, C1.w,
                        C2.x, C2.y, C2.z, C2.w, C3.x, C3.y, C3.z, C3.w};
    float y0 = 0.f, y1 = 0.f, y2 = 0.f, y3 = 0.f;
#pragma unroll
    for (int n = 0; n < 4; ++n) {
      s[n] = fmaf(s[n], dA[n], db * Bv[n]);
      y0 = fmaf(s[n], Cv[n], y0);
      s[n + 4] = fmaf(s[n + 4], dA[n + 4], db * Bv[n + 4]);
      y1 = fmaf(s[n + 4], Cv[n + 4], y1);
      s[n + 8] = fmaf(s[n + 8], dA[n + 8], db * Bv[n + 8]);
      y2 = fmaf(s[n + 8], Cv[n + 8], y2);
      s[n + 12] = fmaf(s[n + 12], dA[n + 12], db * Bv[n + 12]);
      y3 = fmaf(s[n + 12], Cv[n + 12], y3);
    }
    float y = (y0 + y1) + (y2 + y3);
    float gate = zt / (1.f + __expf(-zt));
    gOut[off] = f2bf((y + Dval * ut) * gate);

    off += DI;
    boff += 32;
    d = d_n; ut = ut_n; zt = zt_n;
  }
}

// ---------------------------------------------------------------------------
extern "C" void kernel_launch(void* const* d_in, const int* in_sizes, int n_in,
                              void* d_out, int out_size, void* d_ws,
                              size_t ws_size, hipStream_t stream) {
  const float* hs = (const float*)d_in[0];
  const float* in2 = (const float*)d_in[1];
  const float* w1 = (const float*)d_in[2];
  const float* w2 = (const float*)d_in[3];
  const float* cw = (const float*)d_in[4];
  const float* cb = (const float*)d_in[5];
  const float* xpw = (const float*)d_in[6];
  const float* dtw = (const float*)d_in[7];
  const float* dtb = (const float*)d_in[8];
  const float* alog = (const float*)d_in[9];
  const float* Dv = (const float*)d_in[10];
  const float* ow = (const float*)d_in[11];
  float* out = (float*)d_out;

  const size_t BLE = (size_t)BATCH * LSEQ * DI;   // 8,388,608
  const size_t WN = (size_t)DI * DM;              // 2,097,152
  const size_t SC = (size_t)BATCH * NC * DI * DSTATE;  // 4,194,304

  // Regions (floats), all lifetimes disjoint:
  float* W = (float*)d_ws;
  float* bufX = W;             // BLE: xpreB (bf16, half) -> dB (bf16, half)
  float* M2 = W + BLE;         // BLE/2: hsb -> zb (bf16)
  float* M3 = M2 + BLE / 2;    // BLE/2: in2b -> ub (bf16)
  float* M4 = M3 + BLE / 2;    // BLE/2: wb1|wb2 -> xdblP(8PN)|dtB -> bufG
  float* sEnd = M4 + BLE / 2;  // SC (holds sInit after passB)
  float* sProd = sEnd + SC;    // SC
  float* BC = sProd + SC;      // 131,072 floats
  float* DED = BC + 131072;    // dedicated: owb | xpwB | dtwB

  unsigned short* xpreB = (unsigned short*)bufX;
  unsigned short* dB = (unsigned short*)bufX;
  unsigned short* hsb = (unsigned short*)M2;
  unsigned short* zb = (unsigned short*)M2;
  unsigned short* in2b = (unsigned short*)M3;
  unsigned short* ub = (unsigned short*)M3;
  unsigned short* wb1 = (unsigned short*)M4;
  unsigned short* wb2 = wb1 + WN;
  float* xdblP = M4;                                     // 8*PN floats
  unsigned short* dtB = (unsigned short*)(M4 + 8 * PN);  // 262,144 ushorts
  unsigned short* bufG = (unsigned short*)M4;            // after delta dead
  unsigned short* owb = (unsigned short*)DED;            // WN ushorts
  unsigned short* xpwB = owb + WN;                       // 196,608 ushorts
  unsigned short* dtwB = xpwB + XDR * DI;                // 131,072 ushorts

  const int M = BATCH * LSEQ;  // 4096
  dim3 blk(256);

  // 0. convert ALL bf16 operands in one launch
  cvt_all_kernel<<<G_OW / 256, blk, 0, stream>>>(hs, in2, w1, w2, xpw, dtw, ow,
                                                 hsb, in2b, wb1, wb2, xpwB,
                                                 dtwB, owb);
  // 1+2. x_pre = hs @ w1^T  AND  z = in2 @ w2^T (dual 4-phase 256^2 launch)
  gemm_in12<<<dim3(DI / 256, M / 256, 2), dim3(512), 0, stream>>>(
      hsb, wb1, xpreB, in2b, wb2, zb);
  // 3. u = silu(conv(x_pre) + cb)  (bf16 in/out)
  conv_silu_kernel<<<(M * (DI / 4)) / 256, blk, 0, stream>>>(xpreB, cw, cb,
                                                             ub);
  // 4. x_dbl partials = u @ xpw^T (split-K x8, 256 blocks) + reduce
  gemm_xdbl<<<dim3(M / 128, 8), blk, 0, stream>>>(ub, xpwB, xdblP);
  reduce8x_kernel<<<(M * XDR) / 256, blk, 0, stream>>>(xdblP, dtB, BC);
  // 5. d = softplus(dt @ dtw^T + dtb)  (bf16 out into bufX; xpreB dead)
  gemm_delta<<<dim3(DI / 128, M / 128), blk, 0, stream>>>(
      dtB, dtwB, dtb, dB, DTR, DTR, DTR, DI);
  // 6. chunked scan; passB in-place (sEnd -> sInit); passC emits g bf16
  scan_passA<<<(BATCH * DI * NC) / 256, blk, 0, stream>>>(dB, ub, BC, alog,
                                                          sEnd, sProd);
  scan_passB<<<(BATCH * DI * DSTATE) / 256, blk, 0, stream>>>(sEnd, sProd);
  scan_passC<<<(BATCH * DI * NC) / 256, blk, 0, stream>>>(
      dB, ub, zb, BC, alog, Dv, sEnd, bufG);
  // 7. out = g @ ow^T  (256x64 tile, 2-buffer counted-vmcnt, 256 blocks)
  gemm_out<<<dim3(DM / 64, M / 256), dim3(512), 0, stream>>>(bufG, owb, out);
}

// Round 37
// 214.758 us; speedup vs baseline: 1.0006x; 1.0002x over previous
//
#include <hip/hip_runtime.h>
#include <cstddef>
#include <cmath>

#define BATCH 2
#define LSEQ 2048
#define DM 1024
#define DSTATE 16
#define DI 2048
#define DTR 64
#define XDR 96   // DTR + 2*DSTATE
#define NC 64    // scan chunks
#define TC 32    // timesteps per chunk (NC*TC == LSEQ)
#define PN (4096 * 96)  // per-z x_dbl partial size

using f32x4 = __attribute__((ext_vector_type(4))) float;
using bf16x8 = __attribute__((ext_vector_type(8))) short;

__device__ __forceinline__ unsigned short f2bf(float f) {
  union { float f; unsigned int u; } c; c.f = f;
  unsigned int u = c.u;
  return (unsigned short)((u + 0x7FFFu + ((u >> 16) & 1u)) >> 16);  // RNE
}
__device__ __forceinline__ float bf2f(unsigned short h) {
  union { unsigned int u; float f; } c; c.u = ((unsigned int)h) << 16;
  return c.f;
}
__device__ __forceinline__ unsigned int pack2(float a, float b) {
  return (unsigned int)f2bf(a) | ((unsigned int)f2bf(b) << 16);
}

__device__ __forceinline__ void gl_lds16(const void* g, void* l) {
  __builtin_amdgcn_global_load_lds(
      (const __attribute__((address_space(1))) void*)g,
      (__attribute__((address_space(3))) void*)l, 16, 0, 0);
}

__device__ __forceinline__ float softplus_fast(float x) {
  float ex = __expf(x);
  return (x > 20.f) ? x : __logf(1.f + ex);
}

// dA[n] = q^(n+1), binary-power tree (depth ~4 instead of 15-serial).
__device__ __forceinline__ void pow_tree(float q1, float* dA) {
  float q2 = q1 * q1;
  float q3 = q2 * q1;
  float q4 = q2 * q2;
  float q8 = q4 * q4;
  float q5 = q4 * q1, q6 = q4 * q2, q7 = q4 * q3;
  dA[0] = q1;  dA[1] = q2;  dA[2] = q3;  dA[3] = q4;
  dA[4] = q5;  dA[5] = q6;  dA[6] = q7;  dA[7] = q8;
  dA[8] = q8 * q1;  dA[9] = q8 * q2;  dA[10] = q8 * q3;  dA[11] = q8 * q4;
  dA[12] = q8 * q5; dA[13] = q8 * q6; dA[14] = q8 * q7;  dA[15] = q8 * q8;
}

// ---------------------------------------------------------------------------
// Single-launch f32->bf16 conversion of ALL seven GEMM operands.
// ---------------------------------------------------------------------------
#define G_HS   524288            // BLM/8
#define G_IN2  (G_HS + 524288)
#define G_W1   (G_IN2 + 262144)  // WN/8
#define G_W2   (G_W1 + 262144)
#define G_XPW  (G_W2 + 24576)    // XDR*DI/8
#define G_DTW  (G_XPW + 16384)   // DI*DTR/8
#define G_OW   (G_DTW + 262144)  // total 1,875,968 -> 7328 blocks exactly

__global__ __launch_bounds__(256) void cvt_all_kernel(
    const float* __restrict__ hs, const float* __restrict__ in2,
    const float* __restrict__ w1, const float* __restrict__ w2,
    const float* __restrict__ xpw, const float* __restrict__ dtw,
    const float* __restrict__ ow, unsigned short* __restrict__ hsb,
    unsigned short* __restrict__ in2b, unsigned short* __restrict__ wb1,
    unsigned short* __restrict__ wb2, unsigned short* __restrict__ xpwB,
    unsigned short* __restrict__ dtwB, unsigned short* __restrict__ owb) {
  int i = blockIdx.x * 256 + threadIdx.x;
  const float* s;
  unsigned short* d;
  int k;
  if (i < G_HS)       { s = hs;  d = hsb;  k = i; }
  else if (i < G_IN2) { s = in2; d = in2b; k = i - G_HS; }
  else if (i < G_W1)  { s = w1;  d = wb1;  k = i - G_IN2; }
  else if (i < G_W2)  { s = w2;  d = wb2;  k = i - G_W1; }
  else if (i < G_XPW) { s = xpw; d = xpwB; k = i - G_W2; }
  else if (i < G_DTW) { s = dtw; d = dtwB; k = i - G_XPW; }
  else                { s = ow;  d = owb;  k = i - G_DTW; }
  const float4* sp = reinterpret_cast<const float4*>(s) + (size_t)k * 2;
  float4 a = sp[0], b = sp[1];
  uint4 v = make_uint4(pack2(a.x, a.y), pack2(a.z, a.w), pack2(b.x, b.y),
                       pack2(b.z, b.w));
  *(reinterpret_cast<uint4*>(d) + k) = v;
}

// ---------------------------------------------------------------------------
// Dual in-proj GEMM, 4-phase 256^2 counted-vmcnt schedule.
// BM=BN=256, BK=64, 8 waves (2M x 4N), 512 threads, 128 KiB LDS (2 K-tile
// double buffer).  Per phase: one A-half (4 m-frags) x K=64 = 32 MFMA.
// Stage schedule (target freed by an earlier phase-end barrier):
//   phA: T+1.A -> buf1.A (freed prev phD)   phB: T+2.B -> buf0.B (phA)
//   phC: T+2.A -> buf0.A (phB)              phD: T+3.B -> buf1.B (phC)
// vmcnt(4) at phB/phD (4 loads = 1 tile stay in flight, never 0 in loop).
// ---------------------------------------------------------------------------
__global__ __launch_bounds__(512) void gemm_in12(
    const unsigned short* __restrict__ A0, const unsigned short* __restrict__ B0,
    unsigned short* __restrict__ C0, const unsigned short* __restrict__ A1,
    const unsigned short* __restrict__ B1, unsigned short* __restrict__ C1) {
  __shared__ __align__(16) unsigned short Asm[2][256][64];  // 64 KiB
  __shared__ __align__(16) unsigned short Bsm[2][256][64];  // 64 KiB

  const unsigned short* A = blockIdx.z ? A1 : A0;
  const unsigned short* B = blockIdx.z ? B1 : B0;
  unsigned short* C = blockIdx.z ? C1 : C0;
  const int lda = DM, ldc = DI;  // K = DM = 1024 -> 16 K-tiles of 64

  const int tid = threadIdx.x;
  const int lane = tid & 63;
  const int w = tid >> 6;   // 0..7
  const int wr = w >> 2;    // 0..1  (M half)
  const int wn = w & 3;     // 0..3  (N quarter)

  const int gx = gridDim.x;            // 8
  const int nwg = gx * gridDim.y;      // 128 (per z)
  const int id = blockIdx.y * gx + blockIdx.x;
  const int cpx = nwg >> 3;
  const int lt = (id & 7) * cpx + (id >> 3);
  const size_t m0 = (size_t)(lt / gx) * 256;
  const size_t n0 = (size_t)(lt % gx) * 256;

  const int rsub = lane >> 3;
  const int sslot = (lane & 7) ^ rsub;
  const unsigned short* Ab = A + (m0 + (size_t)rsub) * lda + sslot * 8;
  const unsigned short* Bb = B + (n0 + (size_t)rsub) * lda + sslot * 8;

  const int fr = lane & 15;
  const int q = lane >> 4;
  const int f7 = fr & 7;

  f32x4 acc[8][4] = {};
  bf16x8 bfr[4][2];

// stage a full 256x64 tile of K-tile T: each wave fills 32 rows (4 gl_lds)
#define STA(BUF, T)                                                         \
  {                                                                         \
    const int r0_ = w * 32;                                                 \
    const unsigned short* s_ = Ab + (size_t)r0_ * lda + (T) * 64;           \
    gl_lds16(s_, &Asm[BUF][r0_][0]);                                        \
    gl_lds16(s_ + (size_t)8 * lda, &Asm[BUF][r0_ + 8][0]);                  \
    gl_lds16(s_ + (size_t)16 * lda, &Asm[BUF][r0_ + 16][0]);                \
    gl_lds16(s_ + (size_t)24 * lda, &Asm[BUF][r0_ + 24][0]);                \
  }
#define STB(BUF, T)                                                         \
  {                                                                         \
    const int r0_ = w * 32;                                                 \
    const unsigned short* s_ = Bb + (size_t)r0_ * lda + (T) * 64;           \
    gl_lds16(s_, &Bsm[BUF][r0_][0]);                                        \
    gl_lds16(s_ + (size_t)8 * lda, &Bsm[BUF][r0_ + 8][0]);                  \
    gl_lds16(s_ + (size_t)16 * lda, &Bsm[BUF][r0_ + 16][0]);                \
    gl_lds16(s_ + (size_t)24 * lda, &Bsm[BUF][r0_ + 24][0]);                \
  }

// one phase: ds-load half subtile | stage | [vmcnt] | barrier | lgkm0 | MFMA
#define PH4(BUFI, HALF, LOADB, STG, VM)                                     \
  {                                                                         \
    if (LOADB) {                                                            \
      _Pragma("unroll") for (int j = 0; j < 4; ++j)                         \
          _Pragma("unroll") for (int kk = 0; kk < 2; ++kk)                  \
              bfr[j][kk] = *reinterpret_cast<const bf16x8*>(                \
                  &Bsm[BUFI][wn * 64 + j * 16 + fr]                         \
                      [((kk * 4 + q) ^ f7) << 3]);                          \
    }                                                                       \
    bf16x8 af_[4][2];                                                       \
    _Pragma("unroll") for (int mi = 0; mi < 4; ++mi)                        \
        _Pragma("unroll") for (int kk = 0; kk < 2; ++kk)                    \
            af_[mi][kk] = *reinterpret_cast<const bf16x8*>(                 \
                &Asm[BUFI][wr * 128 + ((HALF)*4 + mi) * 16 + fr]            \
                    [((kk * 4 + q) ^ f7) << 3]);                            \
    STG;                                                                    \
    VM;                                                                     \
    __builtin_amdgcn_s_barrier();                                           \
    asm volatile("s_waitcnt lgkmcnt(0)" ::: "memory");                      \
    __builtin_amdgcn_sched_barrier(0);                                      \
    __builtin_amdgcn_s_setprio(1);                                          \
    _Pragma("unroll") for (int kk = 0; kk < 2; ++kk)                        \
        _Pragma("unroll") for (int mi = 0; mi < 4; ++mi)                    \
            _Pragma("unroll") for (int j = 0; j < 4; ++j)                   \
                acc[(HALF)*4 + mi][j] =                                     \
                    __builtin_amdgcn_mfma_f32_16x16x32_bf16(                \
                        af_[mi][kk], bfr[j][kk], acc[(HALF)*4 + mi][j],     \
                        0, 0, 0);                                           \
    __builtin_amdgcn_s_setprio(0);                                          \
    __builtin_amdgcn_s_barrier();                                           \
  }

#define VMC4_ asm volatile("s_waitcnt vmcnt(4)" ::: "memory")
#define VMC0_ asm volatile("s_waitcnt vmcnt(0)" ::: "memory")
#define NOPS_ ((void)0)

  // prologue: T0.B, T0.A, T1.B; drain T0 (T1.B stays in flight)
  STB(0, 0)
  STA(0, 0)
  STB(1, 1)
  VMC4_;
  __builtin_amdgcn_s_barrier();

#pragma unroll 1
  for (int it = 0; it < 7; ++it) {
    const int t0 = 2 * it, t1 = 2 * it + 1;
    PH4(0, 0, true,  STA(1, t1),     NOPS_)   // phA
    PH4(0, 1, false, STB(0, t0 + 2), VMC4_)   // phB: drain T+1.A (+lingering)
    PH4(1, 0, true,  STA(0, t0 + 2), NOPS_)   // phC
    PH4(1, 1, false, STB(1, t1 + 2), VMC4_)   // phD: drain T+2.B + T+2.A
  }
  // final iteration: tiles 14 (buf0), 15 (buf1); no further staging
  PH4(0, 0, true,  STA(1, 15), NOPS_)
  PH4(0, 1, false, NOPS_,      VMC0_)
  PH4(1, 0, true,  NOPS_, NOPS_)
  PH4(1, 1, false, NOPS_, NOPS_)

#undef STA
#undef STB
#undef PH4

  const int crb = q * 4;
#pragma unroll
  for (int mf = 0; mf < 8; ++mf) {
    size_t row = m0 + wr * 128 + mf * 16 + crb;
#pragma unroll
    for (int j = 0; j < 4; ++j) {
      size_t col = n0 + wn * 64 + j * 16 + fr;
#pragma unroll
      for (int r = 0; r < 4; ++r)
        C[(row + r) * ldc + col] = f2bf(acc[mf][j][r]);
    }
  }
}

// ---------------------------------------------------------------------------
// Out-proj GEMM: out[m,n] = sum_k g[m,k]*ow[n,k].  M=4096, N=DM, K=DI.
// BM=256, BN=64 (256 blocks = 1/CU), 8 waves (4M x 2N), wave tile 64x32.
// 2-buffer counted-vmcnt schedule, one phase per K-tile (16 MFMA).  f32 out.
// ---------------------------------------------------------------------------
__global__ __launch_bounds__(512) void gemm_out(
    const unsigned short* __restrict__ A, const unsigned short* __restrict__ B,
    float* __restrict__ C) {
  __shared__ __align__(16) unsigned short Asm[2][256][64];  // 64 KiB
  __shared__ __align__(16) unsigned short Bsm[2][64][64];   // 16 KiB

  const int lda = DI, ldc = DM;  // K = DI = 2048 -> 32 K-tiles of 64

  const int tid = threadIdx.x;
  const int lane = tid & 63;
  const int w = tid >> 6;    // 0..7
  const int wm = w >> 1;     // 0..3 (M quarter)
  const int wn = w & 1;      // 0..1 (N half)

  const int gx = gridDim.x;        // 16 (N tiles)
  const int nwg = gx * gridDim.y;  // 256
  const int id = blockIdx.y * gx + blockIdx.x;
  const int cpx = nwg >> 3;
  const int lt = (id & 7) * cpx + (id >> 3);
  const size_t m0 = (size_t)(lt / gx) * 256;
  const size_t n0 = (size_t)(lt % gx) * 64;

  const int rsub = lane >> 3;
  const int sslot = (lane & 7) ^ rsub;
  const unsigned short* Ab = A + (m0 + (size_t)rsub) * lda + sslot * 8;
  const unsigned short* Bb = B + (n0 + (size_t)rsub) * lda + sslot * 8;

  const int fr = lane & 15;
  const int q = lane >> 4;
  const int f7 = fr & 7;

  f32x4 acc[4][2] = {};

#define OSTA(BUF, T)                                                        \
  {                                                                         \
    const int r0_ = w * 32;                                                 \
    const unsigned short* s_ = Ab + (size_t)r0_ * lda + (T) * 64;           \
    gl_lds16(s_, &Asm[BUF][r0_][0]);                                        \
    gl_lds16(s_ + (size_t)8 * lda, &Asm[BUF][r0_ + 8][0]);                  \
    gl_lds16(s_ + (size_t)16 * lda, &Asm[BUF][r0_ + 16][0]);                \
    gl_lds16(s_ + (size_t)24 * lda, &Asm[BUF][r0_ + 24][0]);                \
  }
#define OSTB(BUF, T)                                                        \
  {                                                                         \
    const int r0_ = w * 8;                                                  \
    gl_lds16(Bb + (size_t)r0_ * lda + (T) * 64, &Bsm[BUF][r0_][0]);         \
  }

#define OPH(BUFI, STG, VM)                                                  \
  {                                                                         \
    bf16x8 af_[4][2], bf_[2][2];                                            \
    _Pragma("unroll") for (int j = 0; j < 2; ++j)                           \
        _Pragma("unroll") for (int kk = 0; kk < 2; ++kk)                    \
            bf_[j][kk] = *reinterpret_cast<const bf16x8*>(                  \
                &Bsm[BUFI][wn * 32 + j * 16 + fr]                           \
                    [((kk * 4 + q) ^ f7) << 3]);                            \
    _Pragma("unroll") for (int mi = 0; mi < 4; ++mi)                        \
        _Pragma("unroll") for (int kk = 0; kk < 2; ++kk)                    \
            af_[mi][kk] = *reinterpret_cast<const bf16x8*>(                 \
                &Asm[BUFI][wm * 64 + mi * 16 + fr]                          \
                    [((kk * 4 + q) ^ f7) << 3]);                            \
    asm volatile("s_waitcnt lgkmcnt(0)" ::: "memory");                      \
    __builtin_amdgcn_sched_barrier(0);                                      \
    __builtin_amdgcn_s_barrier();                                           \
    STG;                                                                    \
    VM;                                                                     \
    __builtin_amdgcn_s_barrier();                                           \
    __builtin_amdgcn_s_setprio(1);                                          \
    _Pragma("unroll") for (int kk = 0; kk < 2; ++kk)                        \
        _Pragma("unroll") for (int mi = 0; mi < 4; ++mi)                    \
            _Pragma("unroll") for (int j = 0; j < 2; ++j)                   \
                acc[mi][j] = __builtin_amdgcn_mfma_f32_16x16x32_bf16(       \
                    af_[mi][kk], bf_[j][kk], acc[mi][j], 0, 0, 0);          \
    __builtin_amdgcn_s_setprio(0);                                          \
  }

#define OVMC5_ asm volatile("s_waitcnt vmcnt(5)" ::: "memory")
#define OVMC0_ asm volatile("s_waitcnt vmcnt(0)" ::: "memory")
#define ONOP_ ((void)0)

  // prologue: stage T0 -> buf0, T1 -> buf1; drain T0 (T1's 5 in flight)
  OSTA(0, 0) OSTB(0, 0)
  OSTA(1, 1) OSTB(1, 1)
  OVMC5_;
  __builtin_amdgcn_s_barrier();

#pragma unroll 1
  for (int it = 0; it < 15; ++it) {
    const int t0 = 2 * it, t1 = 2 * it + 1;
    OPH(0, { OSTA(0, t0 + 2) OSTB(0, t0 + 2) }, OVMC5_)  // tile t0
    OPH(1, { OSTA(1, t1 + 2) OSTB(1, t1 + 2) }, OVMC5_)  // tile t1
  }
  // tiles 30 (buf0) and 31 (buf1); no further staging
  OPH(0, ONOP_, OVMC0_)
  OPH(1, ONOP_, ONOP_)

#undef OSTA
#undef OSTB
#undef OPH

  const int crb = q * 4;
#pragma unroll
  for (int mf = 0; mf < 4; ++mf) {
    size_t row = m0 + wm * 64 + mf * 16 + crb;
#pragma unroll
    for (int j = 0; j < 2; ++j) {
      size_t col = n0 + wn * 32 + j * 16 + fr;
#pragma unroll
      for (int r = 0; r < 4; ++r)
        C[(row + r) * ldc + col] = acc[mf][j][r];
    }
  }
}

// ---------------------------------------------------------------------------
// Delta GEMM with fused bias+softplus epilogue, bf16 out.
// ---------------------------------------------------------------------------
__global__ __launch_bounds__(256) void gemm_delta(
    const unsigned short* __restrict__ A, const unsigned short* __restrict__ B,
    const float* __restrict__ bias, unsigned short* __restrict__ C, int K,
    int lda, int ldb, int ldc) {
  __shared__ __align__(16) unsigned short As[128][64];
  __shared__ __align__(16) unsigned short Bs[128][64];

  const int tid = threadIdx.x;
  const int lane = tid & 63;
  const int w = tid >> 6;

  const int gx = gridDim.x;
  const int nwg = gx * gridDim.y;
  const int id = blockIdx.y * gx + blockIdx.x;
  const int cpx = nwg >> 3;
  const int lt = (id & 7) * cpx + (id >> 3);
  const size_t m0 = (size_t)(lt / gx) * 128;
  const size_t n0 = (size_t)(lt % gx) * 128;

  const int rsub = lane >> 3;
  const int sslot = (lane & 7) ^ rsub;
  const unsigned short* Ab = A + m0 * lda + (size_t)rsub * lda + sslot * 8;
  const unsigned short* Bb = B + n0 * ldb + (size_t)rsub * ldb + sslot * 8;

  f32x4 acc[4][4] = {};

  const int fr = lane & 15;
  const int q = lane >> 4;
  const int f7 = fr & 7;

  for (int k0 = 0; k0 < K; k0 += 64) {
#pragma unroll
    for (int i = 0; i < 4; ++i) {
      const int r0 = w * 32 + i * 8;
      gl_lds16(Ab + (size_t)r0 * lda + k0, &As[r0][0]);
      gl_lds16(Bb + (size_t)r0 * ldb + k0, &Bs[r0][0]);
    }
    __syncthreads();

    bf16x8 af[4][2], bf_[4][2];
#pragma unroll
    for (int i = 0; i < 4; ++i) {
#pragma unroll
      for (int kk = 0; kk < 2; ++kk) {
        const int sA = (((kk * 4 + q) ^ f7) << 3);
        af[i][kk] = *reinterpret_cast<const bf16x8*>(
            &As[(w >> 1) * 64 + i * 16 + fr][sA]);
        bf_[i][kk] = *reinterpret_cast<const bf16x8*>(
            &Bs[(w & 1) * 64 + i * 16 + fr][sA]);
      }
    }
#pragma unroll
    for (int kk = 0; kk < 2; ++kk)
#pragma unroll
      for (int i = 0; i < 4; ++i)
#pragma unroll
        for (int j = 0; j < 4; ++j)
          acc[i][j] = __builtin_amdgcn_mfma_f32_16x16x32_bf16(
              af[i][kk], bf_[j][kk], acc[i][j], 0, 0, 0);
    __syncthreads();
  }

  const int crb = q * 4;
#pragma unroll
  for (int i = 0; i < 4; ++i) {
    size_t row = m0 + (w >> 1) * 64 + i * 16 + crb;
#pragma unroll
    for (int j = 0; j < 4; ++j) {
      size_t col = n0 + (w & 1) * 64 + j * 16 + fr;
      float bv = bias[col];
#pragma unroll
      for (int r = 0; r < 4; ++r)
        C[(row + r) * ldc + col] = f2bf(softplus_fast(acc[i][j][r] + bv));
    }
  }
}

// ---------------------------------------------------------------------------
// Skinny x_dbl GEMM: P[z][m][c] = sum_{k in z-chunk} u[m][k]*xpw[c][k].
// Split-K x8 (256 blocks -> 1/CU).
// ---------------------------------------------------------------------------
__global__ __launch_bounds__(256) void gemm_xdbl(
    const unsigned short* __restrict__ A,  // u bf16 [4096][2048]
    const unsigned short* __restrict__ B,  // xpw bf16 [96][2048]
    float* __restrict__ P) {               // partials [8][4096][96]
  __shared__ __align__(16) unsigned short As[128][64];
  __shared__ __align__(16) unsigned short Bs[96][64];

  const int tid = threadIdx.x;
  const int lane = tid & 63;
  const int w = tid >> 6;
  const size_t m0 = (size_t)blockIdx.x * 128;
  const int k0base = blockIdx.y * 256;

  const int rsub = lane >> 3;
  const int sslot = (lane & 7) ^ rsub;
  const unsigned short* Ab = A + m0 * DI + (size_t)rsub * DI + sslot * 8;
  const unsigned short* Bb = B + (size_t)rsub * DI + sslot * 8;

  f32x4 acc[4][3] = {};

  const int fr = lane & 15;
  const int q = lane >> 4;
  const int f7 = fr & 7;

  for (int ks = 0; ks < 4; ++ks) {
    const int k0 = k0base + ks * 64;
#pragma unroll
    for (int i = 0; i < 4; ++i) {
      const int r0 = w * 32 + i * 8;
      gl_lds16(Ab + (size_t)r0 * DI + k0, &As[r0][0]);
    }
#pragma unroll
    for (int i = 0; i < 3; ++i) {
      const int r0 = w * 24 + i * 8;
      gl_lds16(Bb + (size_t)r0 * DI + k0, &Bs[r0][0]);
    }
    __syncthreads();

    bf16x8 af[4][2], bf_[3][2];
#pragma unroll
    for (int kk = 0; kk < 2; ++kk) {
      const int sA = (((kk * 4 + q) ^ f7) << 3);
#pragma unroll
      for (int i = 0; i < 4; ++i)
        af[i][kk] = *reinterpret_cast<const bf16x8*>(
            &As[(w >> 1) * 64 + i * 16 + fr][sA]);
#pragma unroll
      for (int j = 0; j < 3; ++j)
        bf_[j][kk] = *reinterpret_cast<const bf16x8*>(
            &Bs[(w & 1) * 48 + j * 16 + fr][sA]);
    }
#pragma unroll
    for (int kk = 0; kk < 2; ++kk)
#pragma unroll
      for (int i = 0; i < 4; ++i)
#pragma unroll
        for (int j = 0; j < 3; ++j)
          acc[i][j] = __builtin_amdgcn_mfma_f32_16x16x32_bf16(
              af[i][kk], bf_[j][kk], acc[i][j], 0, 0, 0);
    __syncthreads();
  }

  float* Pz = P + (size_t)blockIdx.y * PN;
  const int crb = q * 4;
#pragma unroll
  for (int i = 0; i < 4; ++i) {
    size_t row = m0 + (w >> 1) * 64 + i * 16 + crb;
#pragma unroll
    for (int j = 0; j < 3; ++j) {
      int col = (w & 1) * 48 + j * 16 + fr;
#pragma unroll
      for (int r = 0; r < 4; ++r) Pz[(row + r) * XDR + col] = acc[i][j][r];
    }
  }
}

// reduce split-K partials (x8); emit dt bf16 (cols 0..63) + compact B/C f32.
__global__ __launch_bounds__(256) void reduce8x_kernel(
    const float* __restrict__ P, unsigned short* __restrict__ dtB,
    float* __restrict__ BC) {
  int i = blockIdx.x * 256 + threadIdx.x;  // < 4096*96
  int row = i / XDR, col = i - row * XDR;
  float s01 = P[i] + P[PN + i];
  float s23 = P[2 * PN + i] + P[3 * PN + i];
  float s45 = P[4 * PN + i] + P[5 * PN + i];
  float s67 = P[6 * PN + i] + P[7 * PN + i];
  float s = (s01 + s23) + (s45 + s67);
  if (col < 64)
    dtB[row * 64 + col] = f2bf(s);
  else
    BC[row * 32 + (col - 64)] = s;
}

// ---------------------------------------------------------------------------
// Depthwise causal conv (D_CONV=4) + bias + SiLU; bf16 in, bf16 out.
// 4 elems/thread (measured faster than 8/thread — r33 regression).
// ---------------------------------------------------------------------------
__global__ __launch_bounds__(256) void conv_silu_kernel(
    const unsigned short* __restrict__ x, const float* __restrict__ w,
    const float* __restrict__ cb, unsigned short* __restrict__ out) {
  int idx = blockIdx.x * 256 + threadIdx.x;
  int e4 = idx % (DI / 4);
  int bl = idx / (DI / 4);
  int l = bl % LSEQ;
  int e = e4 * 4;

  const float4* cw = reinterpret_cast<const float4*>(w);
  float4 w0 = cw[e], w1 = cw[e + 1], w2 = cw[e + 2], w3 = cw[e + 3];
  float4 acc = *reinterpret_cast<const float4*>(&cb[e]);

#define TAPK(K, COMP)                                                       \
  {                                                                         \
    int ls = l - 3 + (K);                                                   \
    if (ls >= 0) {                                                          \
      uint2 xv = *reinterpret_cast<const uint2*>(                           \
          &x[((size_t)(bl) - 3 + (K)) * DI + e]);                           \
      acc.x = fmaf(bf2f((unsigned short)(xv.x & 0xffff)), w0.COMP, acc.x);  \
      acc.y = fmaf(bf2f((unsigned short)(xv.x >> 16)), w1.COMP, acc.y);     \
      acc.z = fmaf(bf2f((unsigned short)(xv.y & 0xffff)), w2.COMP, acc.z);  \
      acc.w = fmaf(bf2f((unsigned short)(xv.y >> 16)), w3.COMP, acc.w);     \
    }                                                                       \
  }
  TAPK(0, x)
  TAPK(1, y)
  TAPK(2, z)
  TAPK(3, w)
#undef TAPK

  acc.x = acc.x / (1.f + __expf(-acc.x));
  acc.y = acc.y / (1.f + __expf(-acc.y));
  acc.z = acc.z / (1.f + __expf(-acc.z));
  acc.w = acc.w / (1.f + __expf(-acc.w));
  *reinterpret_cast<uint2*>(&out[(size_t)bl * DI + e]) =
      make_uint2(pack2(acc.x, acc.y), pack2(acc.z, acc.w));
}

// ---------------------------------------------------------------------------
// Chunked selective scan, 16 states/thread (round-13 structure).
// aok check via 15 independent __expf.  passA fast path: P[n] = Q^(n+1).
// ---------------------------------------------------------------------------
__global__ __launch_bounds__(256) void scan_passA(
    const unsigned short* __restrict__ dB, const unsigned short* __restrict__ u,
    const float* __restrict__ bc, const float* __restrict__ A_log,
    float* __restrict__ sEnd, float* __restrict__ sProd) {
  int g = blockIdx.x * 256 + threadIdx.x;  // B*E*NC = 262144
  int e = g & (DI - 1);
  int c = (g >> 11) & (NC - 1);
  int b = g >> 17;

  const float nA0 = -__expf(A_log[e * DSTATE]);
  bool aok = true;
#pragma unroll
  for (int n = 1; n < DSTATE; ++n) {
    float nAn = -__expf(A_log[e * DSTATE + n]);
    aok = aok && (fabsf(nAn - (float)(n + 1) * nA0) <= 1e-4f * fabsf(nAn));
  }

  size_t off = ((size_t)b * LSEQ + c * TC) * DI + e;
  size_t boff = ((size_t)b * LSEQ + c * TC) * 32;

  float s[DSTATE], P[DSTATE];
#pragma unroll
  for (int n = 0; n < DSTATE; ++n) { s[n] = 0.f; P[n] = 1.f; }
  float sumd = 0.f;

  float d = bf2f(dB[off]);
  float ut = bf2f(u[off]);

  for (int t = 0; t < TC; ++t) {
    float d_n = 0.f, ut_n = 0.f;
    if (t + 1 < TC) {
      d_n = bf2f(dB[off + DI]);
      ut_n = bf2f(u[off + DI]);
    }

    float db = d * ut;
    float dA[DSTATE];
    if (aok) {
      pow_tree(__expf(d * nA0), dA);
      sumd += d;
    } else {
#pragma unroll
      for (int n = 0; n < DSTATE; ++n) {
        dA[n] = __expf(-d * __expf(A_log[e * DSTATE + n]));
        P[n] *= dA[n];
      }
    }
    const float4* bcp = reinterpret_cast<const float4*>(&bc[boff]);
    float4 B0 = bcp[0], B1 = bcp[1], B2 = bcp[2], B3 = bcp[3];
    float Bv[DSTATE] = {B0.x, B0.y, B0.z, B0.w, B1.x, B1.y, B1.z, B1.w,
                        B2.x, B2.y, B2.z, B2.w, B3.x, B3.y, B3.z, B3.w};
#pragma unroll
    for (int n = 0; n < DSTATE; ++n)
      s[n] = fmaf(s[n], dA[n], db * Bv[n]);
    off += DI;
    boff += 32;
    d = d_n; ut = ut_n;
  }

  if (aok) pow_tree(__expf(sumd * nA0), P);  // P[n] = Q^(n+1)

  size_t o = (((size_t)b * NC + c) * DI + e) * DSTATE;
  float4* se = reinterpret_cast<float4*>(&sEnd[o]);
  float4* sp = reinterpret_cast<float4*>(&sProd[o]);
  se[0] = make_float4(s[0], s[1], s[2], s[3]);
  se[1] = make_float4(s[4], s[5], s[6], s[7]);
  se[2] = make_float4(s[8], s[9], s[10], s[11]);
  se[3] = make_float4(s[12], s[13], s[14], s[15]);
  sp[0] = make_float4(P[0], P[1], P[2], P[3]);
  sp[1] = make_float4(P[4], P[5], P[6], P[7]);
  sp[2] = make_float4(P[8], P[9], P[10], P[11]);
  sp[3] = make_float4(P[12], P[13], P[14], P[15]);
}

// In-place: sEnd[o] is replaced by the chunk's INITIAL state.
__global__ __launch_bounds__(256) void scan_passB(
    float* __restrict__ sEnd, const float* __restrict__ sProd) {
  int g = blockIdx.x * 256 + threadIdx.x;  // 65,536
  int n = g & 15;
  int e = (g >> 4) & (DI - 1);
  int b = g >> 15;
  float s = 0.f;
  for (int c = 0; c < NC; ++c) {
    size_t o = (((size_t)b * NC + c) * DI + e) * DSTATE + n;
    float se = sEnd[o];
    float sp = sProd[o];
    sEnd[o] = s;
    s = fmaf(s, sp, se);
  }
}

__global__ __launch_bounds__(256) void scan_passC(
    const unsigned short* __restrict__ dB, const unsigned short* __restrict__ u,
    const unsigned short* __restrict__ z, const float* __restrict__ bc,
    const float* __restrict__ A_log, const float* __restrict__ Dv,
    const float* __restrict__ sInit, unsigned short* __restrict__ gOut) {
  int g = blockIdx.x * 256 + threadIdx.x;  // 262144
  int e = g & (DI - 1);
  int c = (g >> 11) & (NC - 1);
  int b = g >> 17;

  const float nA0 = -__expf(A_log[e * DSTATE]);
  bool aok = true;
#pragma unroll
  for (int n = 1; n < DSTATE; ++n) {
    float nAn = -__expf(A_log[e * DSTATE + n]);
    aok = aok && (fabsf(nAn - (float)(n + 1) * nA0) <= 1e-4f * fabsf(nAn));
  }
  const float Dval = Dv[e];

  size_t off = ((size_t)b * LSEQ + c * TC) * DI + e;
  size_t boff = ((size_t)b * LSEQ + c * TC) * 32;

  float s[DSTATE];
  {
    size_t o = (((size_t)b * NC + c) * DI + e) * DSTATE;
    const float4* si = reinterpret_cast<const float4*>(&sInit[o]);
    float4 s0 = si[0], s1 = si[1], s2 = si[2], s3 = si[3];
    s[0] = s0.x; s[1] = s0.y; s[2] = s0.z; s[3] = s0.w;
    s[4] = s1.x; s[5] = s1.y; s[6] = s1.z; s[7] = s1.w;
    s[8] = s2.x; s[9] = s2.y; s[10] = s2.z; s[11] = s2.w;
    s[12] = s3.x; s[13] = s3.y; s[14] = s3.z; s[15] = s3.w;
  }

  float d = bf2f(dB[off]);
  float ut = bf2f(u[off]);
  float zt = bf2f(z[off]);

  for (int t = 0; t < TC; ++t) {
    float d_n = 0.f, ut_n = 0.f, zt_n = 0.f;
    if (t + 1 < TC) {
      d_n = bf2f(dB[off + DI]);
      ut_n = bf2f(u[off + DI]);
      zt_n = bf2f(z[off + DI]);
    }

    float db = d * ut;
    float dA[DSTATE];
    if (aok) {
      pow_tree(__expf(d * nA0), dA);
    } else {
#pragma unroll
      for (int n = 0; n < DSTATE; ++n)
        dA[n] = __expf(-d * __expf(A_log[e * DSTATE + n]));
    }
    const float4* bcp = reinterpret_cast<const float4*>(&bc[boff]);
    float4 B0 = bcp[0], B1 = bcp[1], B2 = bcp[2], B3 = bcp[3];
    float4 C0 = bcp[4], C1 = bcp[5], C2 = bcp[6], C3 = bcp[7];
    float Bv[DSTATE] = {B0.x, B0.y, B0.z, B0.w, B1.x, B1.y, B1.z, B1.w,
                        B2.x, B2.y, B2.z, B2.w, B3.x, B3.y, B3.z, B3.w};
    float Cv[DSTATE] = {C0.x, C0.y, C0.z, C0.w, C1.x, C1.y, C1.z, C1.w,
                        C2.x, C2.y, C2.z, C2.w, C3.x, C3.y, C3.z, C3.w};
    float y0 = 0.f, y1 = 0.f, y2 = 0.f, y3 = 0.f;
#pragma unroll
    for (int n = 0; n < 4; ++n) {
      s[n] = fmaf(s[n], dA[n], db * Bv[n]);
      y0 = fmaf(s[n], Cv[n], y0);
      s[n + 4] = fmaf(s[n + 4], dA[n + 4], db * Bv[n + 4]);
      y1 = fmaf(s[n + 4], Cv[n + 4], y1);
      s[n + 8] = fmaf(s[n + 8], dA[n + 8], db * Bv[n + 8]);
      y2 = fmaf(s[n + 8], Cv[n + 8], y2);
      s[n + 12] = fmaf(s[n + 12], dA[n + 12], db * Bv[n + 12]);
      y3 = fmaf(s[n + 12], Cv[n + 12], y3);
    }
    float y = (y0 + y1) + (y2 + y3);
    float gate = zt / (1.f + __expf(-zt));
    gOut[off] = f2bf((y + Dval * ut) * gate);

    off += DI;
    boff += 32;
    d = d_n; ut = ut_n; zt = zt_n;
  }
}

// ---------------------------------------------------------------------------
extern "C" void kernel_launch(void* const* d_in, const int* in_sizes, int n_in,
                              void* d_out, int out_size, void* d_ws,
                              size_t ws_size, hipStream_t stream) {
  const float* hs = (const float*)d_in[0];
  const float* in2 = (const float*)d_in[1];
  const float* w1 = (const float*)d_in[2];
  const float* w2 = (const float*)d_in[3];
  const float* cw = (const float*)d_in[4];
  const float* cb = (const float*)d_in[5];
  const float* xpw = (const float*)d_in[6];
  const float* dtw = (const float*)d_in[7];
  const float* dtb = (const float*)d_in[8];
  const float* alog = (const float*)d_in[9];
  const float* Dv = (const float*)d_in[10];
  const float* ow = (const float*)d_in[11];
  float* out = (float*)d_out;

  const size_t BLE = (size_t)BATCH * LSEQ * DI;   // 8,388,608
  const size_t WN = (size_t)DI * DM;              // 2,097,152
  const size_t SC = (size_t)BATCH * NC * DI * DSTATE;  // 4,194,304

  // Regions (floats), all lifetimes disjoint:
  float* W = (float*)d_ws;
  float* bufX = W;             // BLE: xpreB (bf16, half) -> dB (bf16, half)
  float* M2 = W + BLE;         // BLE/2: hsb -> zb (bf16)
  float* M3 = M2 + BLE / 2;    // BLE/2: in2b -> ub (bf16)
  float* M4 = M3 + BLE / 2;    // BLE/2: wb1|wb2 -> xdblP(8PN)|dtB -> bufG
  float* sEnd = M4 + BLE / 2;  // SC (holds sInit after passB)
  float* sProd = sEnd + SC;    // SC
  float* BC = sProd + SC;      // 131,072 floats
  float* DED = BC + 131072;    // dedicated: owb | xpwB | dtwB

  unsigned short* xpreB = (unsigned short*)bufX;
  unsigned short* dB = (unsigned short*)bufX;
  unsigned short* hsb = (unsigned short*)M2;
  unsigned short* zb = (unsigned short*)M2;
  unsigned short* in2b = (unsigned short*)M3;
  unsigned short* ub = (unsigned short*)M3;
  unsigned short* wb1 = (unsigned short*)M4;
  unsigned short* wb2 = wb1 + WN;
  float* xdblP = M4;                                     // 8*PN floats
  unsigned short* dtB = (unsigned short*)(M4 + 8 * PN);  // 262,144 ushorts
  unsigned short* bufG = (unsigned short*)M4;            // after delta dead
  unsigned short* owb = (unsigned short*)DED;            // WN ushorts
  unsigned short* xpwB = owb + WN;                       // 196,608 ushorts
  unsigned short* dtwB = xpwB + XDR * DI;                // 131,072 ushorts

  const int M = BATCH * LSEQ;  // 4096
  dim3 blk(256);

  // 0. convert ALL bf16 operands in one launch
  cvt_all_kernel<<<G_OW / 256, blk, 0, stream>>>(hs, in2, w1, w2, xpw, dtw, ow,
                                                 hsb, in2b, wb1, wb2, xpwB,
                                                 dtwB, owb);
  // 1+2. x_pre = hs @ w1^T  AND  z = in2 @ w2^T (dual 4-phase 256^2 launch)
  gemm_in12<<<dim3(DI / 256, M / 256, 2), dim3(512), 0, stream>>>(
      hsb, wb1, xpreB, in2b, wb2, zb);
  // 3. u = silu(conv(x_pre) + cb)  (bf16 in/out)
  conv_silu_kernel<<<(M * (DI / 4)) / 256, blk, 0, stream>>>(xpreB, cw, cb,
                                                             ub);
  // 4. x_dbl partials = u @ xpw^T (split-K x8, 256 blocks) + reduce
  gemm_xdbl<<<dim3(M / 128, 8), blk, 0, stream>>>(ub, xpwB, xdblP);
  reduce8x_kernel<<<(M * XDR) / 256, blk, 0, stream>>>(xdblP, dtB, BC);
  // 5. d = softplus(dt @ dtw^T + dtb)  (bf16 out into bufX; xpreB dead)
  gemm_delta<<<dim3(DI / 128, M / 128), blk, 0, stream>>>(
      dtB, dtwB, dtb, dB, DTR, DTR, DTR, DI);
  // 6. chunked scan; passB in-place (sEnd -> sInit); passC emits g bf16
  scan_passA<<<(BATCH * DI * NC) / 256, blk, 0, stream>>>(dB, ub, BC, alog,
                                                          sEnd, sProd);
  scan_passB<<<(BATCH * DI * DSTATE) / 256, blk, 0, stream>>>(sEnd, sProd);
  scan_passC<<<(BATCH * DI * NC) / 256, blk, 0, stream>>>(
      dB, ub, zb, BC, alog, Dv, sEnd, bufG);
  // 7. out = g @ ow^T  (256x64 tile, 2-buffer counted-vmcnt, 256 blocks)
  gemm_out<<<dim3(DM / 64, M / 256), dim3(512), 0, stream>>>(bufG, owb, out);
}